// Round 1
// baseline (2248.437 us; speedup 1.0000x reference)
//
#include <hip/hip_runtime.h>
#include <math.h>

#define N_PTS 262144

// ---------------------------------------------------------------------------
// Kernel 0: deform_vol[b] = sum_e exp[b][e] * bs[e] + mean   (2 x 4 x 32^3)
// ---------------------------------------------------------------------------
__global__ void k_deform_vol(const float* __restrict__ exp_,
                             const float* __restrict__ bs,
                             const float* __restrict__ mean,
                             float* __restrict__ dvol) {
    int idx = blockIdx.x * blockDim.x + threadIdx.x;   // 2 * 131072
    int b = idx >> 17;
    int v = idx & 131071;
    float acc = mean[v];
    #pragma unroll 8
    for (int e = 0; e < 32; ++e)
        acc = fmaf(exp_[b * 32 + e], bs[e * 131072 + v], acc);
    dvol[idx] = acc;
}

// ---------------------------------------------------------------------------
// Kernel 1: fold the (uniform per batch) exp_n part of the density/color
// hidden layers into per-batch biases.
//   sHb[b][j] = sb1[j] + sum_e (exp[b][e]/3) * sW1[216+e][j]
//   cHb[b][j] = cb1[j] + sum_e (exp[b][e]/3) * cW1[243+e][j]
// ---------------------------------------------------------------------------
__global__ void k_hb(const float* __restrict__ exp_,
                     const float* __restrict__ sW1, const float* __restrict__ sb1,
                     const float* __restrict__ cW1, const float* __restrict__ cb1,
                     float* __restrict__ sHb, float* __restrict__ cHb) {
    int b = blockIdx.x;
    int j = threadIdx.x;           // 128
    float a = sb1[j];
    float a2 = cb1[j];
    for (int e = 0; e < 32; ++e) {
        float ev = exp_[b * 32 + e] * (1.0f / 3.0f);
        a  = fmaf(ev, sW1[(216 + e) * 128 + j], a);
        a2 = fmaf(ev, cW1[(243 + e) * 128 + j], a2);
    }
    sHb[b * 128 + j] = a;
    cHb[b * 128 + j] = a2;
}

// ---------------------------------------------------------------------------
// Trilinear sampler on a strided sub-volume.
//   vol: [C][BD][BD][BD], channel stride BD^3; effective grid size S = BD/STEP.
//   p in normalized [0,1] coords (bbox (0,1)); grid = 2p-1; fx = p*S - 0.5.
//   Zero padding outside, matching the reference's valid-mask logic.
// ---------------------------------------------------------------------------
template<int C, int BD, int S, int STEP>
__device__ __forceinline__ void trilerp(const float* __restrict__ vol,
                                        float px, float py, float pz,
                                        float* __restrict__ out) {
    float fx = px * (float)S - 0.5f;
    float fy = py * (float)S - 0.5f;
    float fz = pz * (float)S - 0.5f;
    float x0 = floorf(fx), y0 = floorf(fy), z0 = floorf(fz);
    float wx = fx - x0, wy = fy - y0, wz = fz - z0;
    int ix = (int)x0, iy = (int)y0, iz = (int)z0;
    #pragma unroll
    for (int c = 0; c < C; ++c) out[c] = 0.0f;
    #pragma unroll
    for (int dz = 0; dz < 2; ++dz) {
        #pragma unroll
        for (int dy = 0; dy < 2; ++dy) {
            #pragma unroll
            for (int dx = 0; dx < 2; ++dx) {
                int xi = ix + dx, yi = iy + dy, zi = iz + dz;
                bool valid = (xi >= 0) & (xi < S) & (yi >= 0) & (yi < S) &
                             (zi >= 0) & (zi < S);
                int xc = min(max(xi, 0), S - 1);
                int yc = min(max(yi, 0), S - 1);
                int zc = min(max(zi, 0), S - 1);
                float w = (dz ? wz : 1.0f - wz) * (dy ? wy : 1.0f - wy) *
                          (dx ? wx : 1.0f - wx);
                w = valid ? w : 0.0f;
                int off = ((zc * STEP) * BD + yc * STEP) * BD + xc * STEP;
                #pragma unroll
                for (int c = 0; c < C; ++c)
                    out[c] = fmaf(vol[c * (BD * BD * BD) + off], w, out[c]);
            }
        }
    }
}

// ---------------------------------------------------------------------------
// Main fused kernel. 256 threads handle 64 points.
// LDS x-matrix is k-major: xs[k*64 + p] so GEMM reads are float4 over points.
// Color-MLP input layout in xs rows: [fe 0..215 | ve 216..242].
// fe: rows 0..23 raw feature, 24+48g+j = sin(f_j*2^g), 24+48g+24+j = cos.
// ve: 216..218 raw v, 219+6g+i = sin(v_i*2^g), 222+6g+i = cos.
// dMLP reuses rows 0..107 earlier: 0..11 raw deform, 12+24g+j sin, +12 cos.
// ---------------------------------------------------------------------------
__global__ __launch_bounds__(256) void k_main(
    const float* __restrict__ qp, const float* __restrict__ qv,
    const float* __restrict__ dvol, const float* __restrict__ fvol,
    const float* __restrict__ dW1, const float* __restrict__ db1,
    const float* __restrict__ dW2, const float* __restrict__ db2,
    const float* __restrict__ sW1, const float* __restrict__ sW2,
    const float* __restrict__ sb2,
    const float* __restrict__ cW1, const float* __restrict__ cW2,
    const float* __restrict__ cb2,
    const float* __restrict__ sHb, const float* __restrict__ cHb,
    float* __restrict__ out)
{
    __shared__ __align__(16) float xs[243 * 64];
    __shared__ float red[3 * 16 * 65];
    __shared__ float dp[3 * 64];

    const int t = threadIdx.x;
    const int p = t & 63;
    const int part = t >> 6;            // 0..3
    const int gp0 = blockIdx.x * 64;
    const int b = gp0 / N_PTS;          // blocks never straddle batches
    const int n0 = gp0 - b * N_PTS;
    const int n = n0 + p;
    const float* qpb = qp + b * 3 * N_PTS;
    const float* qvb = qv + b * 3 * N_PTS;

    // ---- Phase 0a: deform interp (3 levels x 4 ch -> xs rows 0..11) ----
    if (part < 3) {
        float px = qpb[n], py = qpb[N_PTS + n], pz = qpb[2 * N_PTS + n];
        const float* dv = dvol + b * 4 * 32768;
        float o[4];
        if (part == 0)      trilerp<4, 32, 32, 1>(dv, px, py, pz, o);
        else if (part == 1) trilerp<4, 32, 16, 2>(dv, px, py, pz, o);
        else                trilerp<4, 32,  8, 4>(dv, px, py, pz, o);
        #pragma unroll
        for (int c = 0; c < 4; ++c) xs[(part * 4 + c) * 64 + p] = o[c];
    }
    __syncthreads();

    // ---- Phase 0b: embed deform (rows 12..107) ----
    {
        const int g = part;
        const float sc = (float)(1 << g);
        #pragma unroll
        for (int j = 0; j < 12; ++j) {
            float v = xs[j * 64 + p] * sc;
            xs[(12 + 24 * g + j) * 64 + p]      = __sinf(v);
            xs[(12 + 24 * g + 12 + j) * 64 + p] = __cosf(v);
        }
    }
    __syncthreads();

    const int pi = (t & 15) * 4;        // 4 points per thread
    const int jg = t >> 4;              // 0..15 hidden-column group

    // ---- Phase 0c: dMLP GEMM 108 -> 64 -> 3 ----
    {
        float acc[4][4];
        #pragma unroll
        for (int pp = 0; pp < 4; ++pp)
            #pragma unroll
            for (int jj = 0; jj < 4; ++jj) acc[pp][jj] = db1[jg * 4 + jj];
        #pragma unroll 2
        for (int k = 0; k < 108; ++k) {
            float4 xv = *(const float4*)&xs[k * 64 + pi];
            float4 wv = *(const float4*)&dW1[k * 64 + jg * 4];
            const float xr[4] = {xv.x, xv.y, xv.z, xv.w};
            const float wr[4] = {wv.x, wv.y, wv.z, wv.w};
            #pragma unroll
            for (int pp = 0; pp < 4; ++pp)
                #pragma unroll
                for (int jj = 0; jj < 4; ++jj)
                    acc[pp][jj] = fmaf(xr[pp], wr[jj], acc[pp][jj]);
        }
        float po[4][3];
        #pragma unroll
        for (int pp = 0; pp < 4; ++pp) { po[pp][0] = po[pp][1] = po[pp][2] = 0.f; }
        #pragma unroll
        for (int jj = 0; jj < 4; ++jj) {
            float w0 = dW2[(jg * 4 + jj) * 3 + 0];
            float w1 = dW2[(jg * 4 + jj) * 3 + 1];
            float w2 = dW2[(jg * 4 + jj) * 3 + 2];
            #pragma unroll
            for (int pp = 0; pp < 4; ++pp) {
                float h = fmaxf(acc[pp][jj], 0.0f);
                po[pp][0] = fmaf(h, w0, po[pp][0]);
                po[pp][1] = fmaf(h, w1, po[pp][1]);
                po[pp][2] = fmaf(h, w2, po[pp][2]);
            }
        }
        #pragma unroll
        for (int pp = 0; pp < 4; ++pp)
            #pragma unroll
            for (int c = 0; c < 3; ++c)
                red[(c * 16 + jg) * 65 + pi + pp] = po[pp][c];
    }
    __syncthreads();
    if (t < 64) {
        #pragma unroll
        for (int c = 0; c < 3; ++c) {
            float v = db2[c];
            for (int g2 = 0; g2 < 16; ++g2) v += red[(c * 16 + g2) * 65 + t];
            out[(b * 3 + c) * N_PTS + n0 + t] = v;                 // offset
            dp[c * 64 + t] = fmaf(v, 0.1f, qpb[c * N_PTS + n0 + t]); // deformed
        }
    }
    __syncthreads();

    // ---- Phase A: feature interp (3 levels x 8 ch -> xs rows 0..23) ----
    if (part < 3) {
        float px = dp[p], py = dp[64 + p], pz = dp[128 + p];
        float o[8];
        if (part == 0)      trilerp<8, 64, 64, 1>(fvol, px, py, pz, o);
        else if (part == 1) trilerp<8, 64, 32, 2>(fvol, px, py, pz, o);
        else                trilerp<8, 64, 16, 4>(fvol, px, py, pz, o);
        #pragma unroll
        for (int c = 0; c < 8; ++c) xs[(part * 8 + c) * 64 + p] = o[c];
    }
    __syncthreads();

    // ---- Phase B: embed feature (rows 24..215) + view embed (rows 216..242) --
    {
        const int g = part;
        const float sc = (float)(1 << g);
        #pragma unroll
        for (int j = 0; j < 24; ++j) {
            float v = xs[j * 64 + p] * sc;
            xs[(24 + 48 * g + j) * 64 + p]      = __sinf(v);
            xs[(24 + 48 * g + 24 + j) * 64 + p] = __cosf(v);
        }
        float v0 = qvb[n], v1 = qvb[N_PTS + n], v2 = qvb[2 * N_PTS + n];
        if (g == 0) {
            xs[(216) * 64 + p] = v0;
            xs[(217) * 64 + p] = v1;
            xs[(218) * 64 + p] = v2;
        }
        xs[(219 + 6 * g + 0) * 64 + p] = __sinf(v0 * sc);
        xs[(219 + 6 * g + 1) * 64 + p] = __sinf(v1 * sc);
        xs[(219 + 6 * g + 2) * 64 + p] = __sinf(v2 * sc);
        xs[(222 + 6 * g + 0) * 64 + p] = __cosf(v0 * sc);
        xs[(222 + 6 * g + 1) * 64 + p] = __cosf(v1 * sc);
        xs[(222 + 6 * g + 2) * 64 + p] = __cosf(v2 * sc);
    }
    __syncthreads();

    // ---- Phase C: density GEMM K=216 (exp part folded into sHb) ----
    {
        float acc[4][8];
        #pragma unroll
        for (int pp = 0; pp < 4; ++pp)
            #pragma unroll
            for (int jj = 0; jj < 8; ++jj) acc[pp][jj] = sHb[b * 128 + jg * 8 + jj];
        #pragma unroll 2
        for (int k = 0; k < 216; ++k) {
            float4 xv = *(const float4*)&xs[k * 64 + pi];
            float4 w0 = *(const float4*)&sW1[k * 128 + jg * 8];
            float4 w1 = *(const float4*)&sW1[k * 128 + jg * 8 + 4];
            const float xr[4] = {xv.x, xv.y, xv.z, xv.w};
            const float wr[8] = {w0.x, w0.y, w0.z, w0.w, w1.x, w1.y, w1.z, w1.w};
            #pragma unroll
            for (int pp = 0; pp < 4; ++pp)
                #pragma unroll
                for (int jj = 0; jj < 8; ++jj)
                    acc[pp][jj] = fmaf(xr[pp], wr[jj], acc[pp][jj]);
        }
        float pd[4] = {0.f, 0.f, 0.f, 0.f};
        #pragma unroll
        for (int jj = 0; jj < 8; ++jj) {
            float w = sW2[jg * 8 + jj];
            #pragma unroll
            for (int pp = 0; pp < 4; ++pp)
                pd[pp] = fmaf(fmaxf(acc[pp][jj], 0.0f), w, pd[pp]);
        }
        #pragma unroll
        for (int pp = 0; pp < 4; ++pp) red[jg * 65 + pi + pp] = pd[pp];
    }
    __syncthreads();
    if (t < 64) {
        float v = sb2[0];
        for (int g2 = 0; g2 < 16; ++g2) v += red[g2 * 65 + t];
        out[6 * N_PTS + b * N_PTS + n0 + t] = v;                   // density
    }
    __syncthreads();

    // ---- Phase D: color GEMM K=243 (exp part folded into cHb) ----
    {
        float acc[4][8];
        #pragma unroll
        for (int pp = 0; pp < 4; ++pp)
            #pragma unroll
            for (int jj = 0; jj < 8; ++jj) acc[pp][jj] = cHb[b * 128 + jg * 8 + jj];
        #pragma unroll 2
        for (int k = 0; k < 243; ++k) {
            float4 xv = *(const float4*)&xs[k * 64 + pi];
            float4 w0 = *(const float4*)&cW1[k * 128 + jg * 8];
            float4 w1 = *(const float4*)&cW1[k * 128 + jg * 8 + 4];
            const float xr[4] = {xv.x, xv.y, xv.z, xv.w};
            const float wr[8] = {w0.x, w0.y, w0.z, w0.w, w1.x, w1.y, w1.z, w1.w};
            #pragma unroll
            for (int pp = 0; pp < 4; ++pp)
                #pragma unroll
                for (int jj = 0; jj < 8; ++jj)
                    acc[pp][jj] = fmaf(xr[pp], wr[jj], acc[pp][jj]);
        }
        float pc[4][3];
        #pragma unroll
        for (int pp = 0; pp < 4; ++pp) { pc[pp][0] = pc[pp][1] = pc[pp][2] = 0.f; }
        #pragma unroll
        for (int jj = 0; jj < 8; ++jj) {
            float w0 = cW2[(jg * 8 + jj) * 3 + 0];
            float w1 = cW2[(jg * 8 + jj) * 3 + 1];
            float w2 = cW2[(jg * 8 + jj) * 3 + 2];
            #pragma unroll
            for (int pp = 0; pp < 4; ++pp) {
                float h = fmaxf(acc[pp][jj], 0.0f);
                pc[pp][0] = fmaf(h, w0, pc[pp][0]);
                pc[pp][1] = fmaf(h, w1, pc[pp][1]);
                pc[pp][2] = fmaf(h, w2, pc[pp][2]);
            }
        }
        #pragma unroll
        for (int pp = 0; pp < 4; ++pp)
            #pragma unroll
            for (int c = 0; c < 3; ++c)
                red[(c * 16 + jg) * 65 + pi + pp] = pc[pp][c];
    }
    __syncthreads();
    if (t < 64) {
        #pragma unroll
        for (int c = 0; c < 3; ++c) {
            float v = cb2[c];
            for (int g2 = 0; g2 < 16; ++g2) v += red[(c * 16 + g2) * 65 + t];
            v = 1.0f / (1.0f + __expf(-v));
            out[8 * N_PTS + (b * 3 + c) * N_PTS + n0 + t] = v;     // color
        }
    }
}

// ---------------------------------------------------------------------------
extern "C" void kernel_launch(void* const* d_in, const int* in_sizes, int n_in,
                              void* d_out, int out_size, void* d_ws, size_t ws_size,
                              hipStream_t stream) {
    const float* qp   = (const float*)d_in[0];
    const float* qv   = (const float*)d_in[1];
    const float* exp_ = (const float*)d_in[2];
    const float* bs   = (const float*)d_in[3];
    const float* mean = (const float*)d_in[4];
    const float* fvol = (const float*)d_in[5];
    const float* dW1  = (const float*)d_in[6];
    const float* db1  = (const float*)d_in[7];
    const float* dW2  = (const float*)d_in[8];
    const float* db2  = (const float*)d_in[9];
    const float* sW1  = (const float*)d_in[10];
    const float* sb1  = (const float*)d_in[11];
    const float* sW2  = (const float*)d_in[12];
    const float* sb2  = (const float*)d_in[13];
    const float* cW1  = (const float*)d_in[14];
    const float* cb1  = (const float*)d_in[15];
    const float* cW2  = (const float*)d_in[16];
    const float* cb2  = (const float*)d_in[17];

    float* out  = (float*)d_out;
    float* ws   = (float*)d_ws;
    float* dvol = ws;              // 262144 floats
    float* sHb  = ws + 262144;     // 256 floats
    float* cHb  = ws + 262400;     // 256 floats

    k_deform_vol<<<1024, 256, 0, stream>>>(exp_, bs, mean, dvol);
    k_hb<<<2, 128, 0, stream>>>(exp_, sW1, sb1, cW1, cb1, sHb, cHb);
    k_main<<<(2 * N_PTS) / 64, 256, 0, stream>>>(
        qp, qv, dvol, fvol, dW1, db1, dW2, db2,
        sW1, sW2, sb2, cW1, cW2, cb2, sHb, cHb, out);
}

// Round 2
// 530.083 us; speedup vs baseline: 4.2417x; 4.2417x over previous
//
#include <hip/hip_runtime.h>
#include <math.h>

#define NPTS 262144

typedef __attribute__((ext_vector_type(4))) float f32x4;
typedef __attribute__((ext_vector_type(8))) short s16x8;

__device__ __forceinline__ unsigned short f2bf(float f) {
    union { float f; unsigned u; } v; v.f = f;
    unsigned u = v.u;
    return (unsigned short)((u + 0x7fffu + ((u >> 16) & 1u)) >> 16);
}
__device__ __forceinline__ float bf2f(unsigned short h) {
    union { unsigned u; float f; } v; v.u = ((unsigned)h) << 16;
    return v.f;
}

// A-fragment address (bf16-element units) for mfma_f32_16x16x32_bf16.
// Lane l holds row = l&15, k = kt*32 + 4*(l>>4) + (j&3) + 16*(j>>2), j=0..7.
// xfrag layout: [kt][mt=8][lane=64][j=8].
__device__ __forceinline__ int fragAddr(int p, int k) {
    int kt = k >> 5, kk = k & 31;
    int lane = (((kk & 15) >> 2) << 4) | (p & 15);
    int j = ((kk >> 4) << 2) | (kk & 3);
    int mt = p >> 4;
    return (((kt * 8 + mt) * 64) + lane) * 8 + j;
}

// ---------------------------------------------------------------------------
// deform_vol, channels-last: dvt[b][v][c], v = (z*32+y)*32+x, c<4
// ---------------------------------------------------------------------------
__global__ void k_deform_vol_t(const float* __restrict__ exp_,
                               const float* __restrict__ bs,
                               const float* __restrict__ mean,
                               float* __restrict__ dvt) {
    int idx = blockIdx.x * blockDim.x + threadIdx.x;   // 262144
    int c = idx & 3;
    int v = (idx >> 2) & 32767;
    int b = idx >> 17;
    float acc = mean[c * 32768 + v];
    #pragma unroll 8
    for (int e = 0; e < 32; ++e)
        acc = fmaf(exp_[b * 32 + e], bs[(e * 4 + c) * 32768 + v], acc);
    dvt[idx] = acc;
}

// ---------------------------------------------------------------------------
// feature volume transpose: fvt[v][c] = fvol[c][v]
// ---------------------------------------------------------------------------
__global__ void k_ftr(const float* __restrict__ fvol, float* __restrict__ fvt) {
    int i = blockIdx.x * blockDim.x + threadIdx.x;     // 2097152
    int c = i >> 18;
    int v = i & 262143;
    fvt[v * 8 + c] = fvol[i];
}

// ---------------------------------------------------------------------------
// fold per-batch exp contribution into hidden biases
// ---------------------------------------------------------------------------
__global__ void k_hb(const float* __restrict__ exp_,
                     const float* __restrict__ sW1, const float* __restrict__ sb1,
                     const float* __restrict__ cW1, const float* __restrict__ cb1,
                     float* __restrict__ sHb, float* __restrict__ cHb) {
    int b = blockIdx.x;
    int j = threadIdx.x;           // 128
    float a = sb1[j];
    float a2 = cb1[j];
    for (int e = 0; e < 32; ++e) {
        float ev = exp_[b * 32 + e] * (1.0f / 3.0f);
        a  = fmaf(ev, sW1[(216 + e) * 128 + j], a);
        a2 = fmaf(ev, cW1[(243 + e) * 128 + j], a2);
    }
    sHb[b * 128 + j] = a;
    cHb[b * 128 + j] = a2;
}

// ---------------------------------------------------------------------------
// Weight -> B-fragment tables (bf16, optional hi/lo split).
// B frag: lane l holds col n = nt*16 + (l&15), k = kt*32 + 4*(l>>4)+(j&3)+16*(j>>2)
// layout [nt][kt][lane][8].  mode 0: row = k<Ksrc ? k : -1.
// mode 1 (cW1): 0..215 -> k ; 224..250 -> k-8 (ve rows 216..242); else -1.
// ---------------------------------------------------------------------------
__global__ void k_wprep(const float* __restrict__ src,
                        unsigned short* __restrict__ dhi,
                        unsigned short* __restrict__ dlo,
                        int KT, int Nsrc, int Ksrc, int mode, int total) {
    int i = blockIdx.x * 256 + threadIdx.x;
    if (i >= total) return;
    int j = i & 7, lane = (i >> 3) & 63;
    int tile = i >> 9;
    int kt = tile % KT, nt = tile / KT;
    int n = nt * 16 + (lane & 15);
    int k = kt * 32 + ((lane >> 4) << 2) + (j & 3) + ((j >> 2) << 4);
    int row;
    if (mode == 0) row = (k < Ksrc) ? k : -1;
    else {
        if (k < 216) row = k;
        else if (k >= 224 && k < 251) row = k - 8;
        else row = -1;
    }
    float v = (row >= 0 && n < Nsrc) ? src[row * Nsrc + n] : 0.0f;
    unsigned short h = f2bf(v);
    dhi[i] = h;
    if (dlo) dlo[i] = f2bf(v - bf2f(h));
}

// ---------------------------------------------------------------------------
// channels-last trilinear gather
// ---------------------------------------------------------------------------
template<int S, int STEP, int DIM, int NC>
__device__ __forceinline__ void lerp_cl(const float* __restrict__ vol,
                                        float px, float py, float pz,
                                        float* __restrict__ o) {
    float fx = px * (float)S - 0.5f;
    float fy = py * (float)S - 0.5f;
    float fz = pz * (float)S - 0.5f;
    float x0 = floorf(fx), y0 = floorf(fy), z0 = floorf(fz);
    float wx = fx - x0, wy = fy - y0, wz = fz - z0;
    int ix = (int)x0, iy = (int)y0, iz = (int)z0;
    #pragma unroll
    for (int c = 0; c < NC; ++c) o[c] = 0.0f;
    #pragma unroll
    for (int dz = 0; dz < 2; ++dz)
    #pragma unroll
    for (int dy = 0; dy < 2; ++dy)
    #pragma unroll
    for (int dx = 0; dx < 2; ++dx) {
        int xi = ix + dx, yi = iy + dy, zi = iz + dz;
        bool valid = (xi >= 0) & (xi < S) & (yi >= 0) & (yi < S) & (zi >= 0) & (zi < S);
        int xc = min(max(xi, 0), S - 1);
        int yc = min(max(yi, 0), S - 1);
        int zc = min(max(zi, 0), S - 1);
        float w = (dz ? wz : 1.f - wz) * (dy ? wy : 1.f - wy) * (dx ? wx : 1.f - wx);
        w = valid ? w : 0.f;
        const float4* q = (const float4*)(vol +
            (size_t)(((zc * STEP) * DIM + yc * STEP) * DIM + xc * STEP) * NC);
        float4 v0 = q[0];
        o[0] = fmaf(v0.x, w, o[0]); o[1] = fmaf(v0.y, w, o[1]);
        o[2] = fmaf(v0.z, w, o[2]); o[3] = fmaf(v0.w, w, o[3]);
        if (NC == 8) {
            float4 v1 = q[1];
            o[4] = fmaf(v1.x, w, o[4]); o[5] = fmaf(v1.y, w, o[5]);
            o[6] = fmaf(v1.z, w, o[6]); o[7] = fmaf(v1.w, w, o[7]);
        }
    }
}

// channel-major fallback (round-1 proven)
template<int C, int BD, int S, int STEP>
__device__ __forceinline__ void trilerp_cm(const float* __restrict__ vol,
                                           float px, float py, float pz,
                                           float* __restrict__ out) {
    float fx = px * (float)S - 0.5f;
    float fy = py * (float)S - 0.5f;
    float fz = pz * (float)S - 0.5f;
    float x0 = floorf(fx), y0 = floorf(fy), z0 = floorf(fz);
    float wx = fx - x0, wy = fy - y0, wz = fz - z0;
    int ix = (int)x0, iy = (int)y0, iz = (int)z0;
    #pragma unroll
    for (int c = 0; c < C; ++c) out[c] = 0.0f;
    #pragma unroll
    for (int dz = 0; dz < 2; ++dz)
    #pragma unroll
    for (int dy = 0; dy < 2; ++dy)
    #pragma unroll
    for (int dx = 0; dx < 2; ++dx) {
        int xi = ix + dx, yi = iy + dy, zi = iz + dz;
        bool valid = (xi >= 0) & (xi < S) & (yi >= 0) & (yi < S) & (zi >= 0) & (zi < S);
        int xc = min(max(xi, 0), S - 1);
        int yc = min(max(yi, 0), S - 1);
        int zc = min(max(zi, 0), S - 1);
        float w = (dz ? wz : 1.f - wz) * (dy ? wy : 1.f - wy) * (dx ? wx : 1.f - wx);
        w = valid ? w : 0.f;
        int off = ((zc * STEP) * BD + yc * STEP) * BD + xc * STEP;
        #pragma unroll
        for (int c = 0; c < C; ++c)
            out[c] = fmaf(vol[c * (BD * BD * BD) + off], w, out[c]);
    }
}

#define MFMA(a, b, c) __builtin_amdgcn_mfma_f32_16x16x32_bf16((a), (b), (c), 0, 0, 0)

// ---------------------------------------------------------------------------
// Main fused kernel: 128 points / block, 256 threads = 4 waves.
// ---------------------------------------------------------------------------
template<bool CL>
__global__ __launch_bounds__(256, 2) void k_main(
    const float* __restrict__ qp, const float* __restrict__ qv,
    const float* __restrict__ dvt, const float* __restrict__ fvol,
    const float* __restrict__ db1, const float* __restrict__ db2,
    const float* __restrict__ sb2, const float* __restrict__ cb2,
    const float* __restrict__ sHb, const float* __restrict__ cHb,
    const unsigned short* __restrict__ dW1h, const unsigned short* __restrict__ dW1l,
    const unsigned short* __restrict__ sW1h, const unsigned short* __restrict__ sW1l,
    const unsigned short* __restrict__ cW1f,
    const unsigned short* __restrict__ dW2f, const unsigned short* __restrict__ sW2f,
    const unsigned short* __restrict__ cW2f,
    float* __restrict__ out)
{
    __shared__ __align__(16) unsigned short xfrag[32768];   // 64 KB: 8kt x 8mt x 64 x 8
    __shared__ float raw[24 * 128];                          // 12 KB
    __shared__ float dp[3 * 128];                            // 1.5 KB

    const int t = threadIdx.x;
    const int lane = t & 63;
    const int w = t >> 6;
    const int gp0 = blockIdx.x * 128;
    const int b = gp0 / NPTS;
    const int n0 = gp0 - b * NPTS;
    const float* qpb = qp + b * 3 * NPTS;
    const float* qvb = qv + b * 3 * NPTS;

    // ---- Phase 1: deform interp -> raw[0..11] ----
    {
        const float* dv = dvt + b * 131072;
        for (int task = t; task < 384; task += 256) {
            int p = task & 127, lvl = task >> 7;
            int n = n0 + p;
            float px = qpb[n], py = qpb[NPTS + n], pz = qpb[2 * NPTS + n];
            float o[4];
            if (lvl == 0)      lerp_cl<32, 1, 32, 4>(dv, px, py, pz, o);
            else if (lvl == 1) lerp_cl<16, 2, 32, 4>(dv, px, py, pz, o);
            else               lerp_cl< 8, 4, 32, 4>(dv, px, py, pz, o);
            #pragma unroll
            for (int c = 0; c < 4; ++c) raw[(lvl * 4 + c) * 128 + p] = o[c];
        }
    }
    __syncthreads();

    // ---- Phase 2: embed deform -> X_d frags (K=128, kt 0..3) ----
    {
        int p = t & 127, hf = t >> 7;
        for (int k = hf * 64; k < hf * 64 + 64; ++k) {
            float val;
            if (k < 12) val = raw[k * 128 + p];
            else if (k < 108) {
                int g = (k - 12) / 24, r = (k - 12) % 24;
                float sc = (float)(1 << g);
                float x = raw[(r % 12) * 128 + p] * sc;
                val = (r < 12) ? __sinf(x) : __cosf(x);
            } else val = 0.f;
            xfrag[fragAddr(p, k)] = f2bf(val);
        }
    }
    __syncthreads();

    // ---- Phase 3: dMLP layer1 (K=128, N=64; wave w -> nt=w; W hi/lo split) ----
    {
        f32x4 acc[8];
        float bias = db1[w * 16 + (lane & 15)];
        #pragma unroll
        for (int mt = 0; mt < 8; ++mt) acc[mt] = (f32x4){bias, bias, bias, bias};
        #pragma unroll 1
        for (int kt = 0; kt < 4; ++kt) {
            s16x8 bh = *(const s16x8*)&dW1h[((w * 4 + kt) * 64 + lane) * 8];
            s16x8 bl = *(const s16x8*)&dW1l[((w * 4 + kt) * 64 + lane) * 8];
            #pragma unroll
            for (int mt = 0; mt < 8; ++mt) {
                s16x8 a = *(const s16x8*)&xfrag[((kt * 8 + mt) * 64 + lane) * 8];
                acc[mt] = MFMA(a, bh, acc[mt]);
                acc[mt] = MFMA(a, bl, acc[mt]);
            }
        }
        // relu -> H_d frags at k = 128 + j (kt 4..5)
        int j = w * 16 + (lane & 15);
        #pragma unroll
        for (int mt = 0; mt < 8; ++mt)
            #pragma unroll
            for (int i = 0; i < 4; ++i) {
                int p = mt * 16 + ((lane >> 4) << 2) + i;
                xfrag[fragAddr(p, 128 + j)] = f2bf(fmaxf(acc[mt][i], 0.f));
            }
    }
    __syncthreads();

    // ---- Phase 4: dMLP layer2 (K=64, N=16 padded; wave w -> mt {2w,2w+1}) ----
    {
        f32x4 acc[2] = {(f32x4){0,0,0,0}, (f32x4){0,0,0,0}};
        #pragma unroll
        for (int kt = 0; kt < 2; ++kt) {
            s16x8 bb = *(const s16x8*)&dW2f[(kt * 64 + lane) * 8];
            #pragma unroll
            for (int q = 0; q < 2; ++q) {
                int mt = 2 * w + q;
                s16x8 a = *(const s16x8*)&xfrag[(((4 + kt) * 8 + mt) * 64 + lane) * 8];
                acc[q] = MFMA(a, bb, acc[q]);
            }
        }
        int col = lane & 15;
        if (col < 3) {
            #pragma unroll
            for (int q = 0; q < 2; ++q)
                #pragma unroll
                for (int i = 0; i < 4; ++i) {
                    int p = (2 * w + q) * 16 + ((lane >> 4) << 2) + i;
                    float v = acc[q][i] + db2[col];
                    out[(b * 3 + col) * NPTS + n0 + p] = v;
                    dp[col * 128 + p] = fmaf(v, 0.1f, qpb[col * NPTS + n0 + p]);
                }
        }
    }
    __syncthreads();

    // ---- Phase 5: feature interp -> raw[0..23] ----
    {
        for (int task = t; task < 384; task += 256) {
            int p = task & 127, lvl = task >> 7;
            float px = dp[p], py = dp[128 + p], pz = dp[256 + p];
            float o[8];
            if (CL) {
                if (lvl == 0)      lerp_cl<64, 1, 64, 8>(fvol, px, py, pz, o);
                else if (lvl == 1) lerp_cl<32, 2, 64, 8>(fvol, px, py, pz, o);
                else               lerp_cl<16, 4, 64, 8>(fvol, px, py, pz, o);
            } else {
                if (lvl == 0)      trilerp_cm<8, 64, 64, 1>(fvol, px, py, pz, o);
                else if (lvl == 1) trilerp_cm<8, 64, 32, 2>(fvol, px, py, pz, o);
                else               trilerp_cm<8, 64, 16, 4>(fvol, px, py, pz, o);
            }
            #pragma unroll
            for (int c = 0; c < 8; ++c) raw[(lvl * 8 + c) * 128 + p] = o[c];
        }
    }
    __syncthreads();

    // ---- Phase 6: embed feature+view -> X frags (K=256, kt 0..7) ----
    // rows: 0..23 raw, 24..215 sincos, 216..223 zero, 224..250 ve, 251..255 zero
    {
        int p = t & 127, hf = t >> 7;
        int n = n0 + p;
        float vv[3] = {qvb[n], qvb[NPTS + n], qvb[2 * NPTS + n]};
        for (int k = hf * 128; k < hf * 128 + 128; ++k) {
            float val;
            if (k < 24) val = raw[k * 128 + p];
            else if (k < 216) {
                int g = (k - 24) / 48, r = (k - 24) % 48;
                float sc = (float)(1 << g);
                float x = raw[(r % 24) * 128 + p] * sc;
                val = (r < 24) ? __sinf(x) : __cosf(x);
            } else if (k < 224) val = 0.f;
            else if (k < 251) {
                int idx = k - 224;
                if (idx < 3) val = vv[idx];
                else {
                    int g = (idx - 3) / 6, r = (idx - 3) % 6;
                    float sc = (float)(1 << g);
                    val = (r < 3) ? __sinf(vv[r] * sc) : __cosf(vv[r % 3] * sc);
                }
            } else val = 0.f;
            xfrag[fragAddr(p, k)] = f2bf(val);
        }
    }
    __syncthreads();

    // ---- Phase 7: density L1 (K=224, hi/lo) + color L1 (K=256, single) ----
    f32x4 accs[8][2], accc[8][2];
    {
        int nl = lane & 15;
        #pragma unroll
        for (int q = 0; q < 2; ++q) {
            float bsv = sHb[b * 128 + (2 * w + q) * 16 + nl];
            float bcv = cHb[b * 128 + (2 * w + q) * 16 + nl];
            #pragma unroll
            for (int mt = 0; mt < 8; ++mt) {
                accs[mt][q] = (f32x4){bsv, bsv, bsv, bsv};
                accc[mt][q] = (f32x4){bcv, bcv, bcv, bcv};
            }
        }
        #pragma unroll 1
        for (int kt = 0; kt < 7; ++kt) {
            s16x8 bh0 = *(const s16x8*)&sW1h[(((2 * w    ) * 7 + kt) * 64 + lane) * 8];
            s16x8 bl0 = *(const s16x8*)&sW1l[(((2 * w    ) * 7 + kt) * 64 + lane) * 8];
            s16x8 bh1 = *(const s16x8*)&sW1h[(((2 * w + 1) * 7 + kt) * 64 + lane) * 8];
            s16x8 bl1 = *(const s16x8*)&sW1l[(((2 * w + 1) * 7 + kt) * 64 + lane) * 8];
            #pragma unroll
            for (int mt = 0; mt < 8; ++mt) {
                s16x8 a = *(const s16x8*)&xfrag[((kt * 8 + mt) * 64 + lane) * 8];
                accs[mt][0] = MFMA(a, bh0, accs[mt][0]);
                accs[mt][0] = MFMA(a, bl0, accs[mt][0]);
                accs[mt][1] = MFMA(a, bh1, accs[mt][1]);
                accs[mt][1] = MFMA(a, bl1, accs[mt][1]);
            }
        }
        #pragma unroll 1
        for (int kt = 0; kt < 8; ++kt) {
            s16x8 b0 = *(const s16x8*)&cW1f[(((2 * w    ) * 8 + kt) * 64 + lane) * 8];
            s16x8 b1 = *(const s16x8*)&cW1f[(((2 * w + 1) * 8 + kt) * 64 + lane) * 8];
            #pragma unroll
            for (int mt = 0; mt < 8; ++mt) {
                s16x8 a = *(const s16x8*)&xfrag[((kt * 8 + mt) * 64 + lane) * 8];
                accc[mt][0] = MFMA(a, b0, accc[mt][0]);
                accc[mt][1] = MFMA(a, b1, accc[mt][1]);
            }
        }
    }
    __syncthreads();

    // ---- Phase 8: relu -> H_s frags (kt 0..3), H_c frags (kt 4..7) ----
    {
        #pragma unroll
        for (int q = 0; q < 2; ++q) {
            int j = (2 * w + q) * 16 + (lane & 15);
            #pragma unroll
            for (int mt = 0; mt < 8; ++mt)
                #pragma unroll
                for (int i = 0; i < 4; ++i) {
                    int p = mt * 16 + ((lane >> 4) << 2) + i;
                    xfrag[fragAddr(p, j)]       = f2bf(fmaxf(accs[mt][q][i], 0.f));
                    xfrag[fragAddr(p, 128 + j)] = f2bf(fmaxf(accc[mt][q][i], 0.f));
                }
        }
    }
    __syncthreads();

    // ---- Phase 9: density L2 + color L2 (K=128 each; wave w -> mt {2w,2w+1}) --
    {
        f32x4 as[2] = {(f32x4){0,0,0,0}, (f32x4){0,0,0,0}};
        f32x4 ac[2] = {(f32x4){0,0,0,0}, (f32x4){0,0,0,0}};
        #pragma unroll
        for (int kt = 0; kt < 4; ++kt) {
            s16x8 bsv = *(const s16x8*)&sW2f[(kt * 64 + lane) * 8];
            s16x8 bcv = *(const s16x8*)&cW2f[(kt * 64 + lane) * 8];
            #pragma unroll
            for (int q = 0; q < 2; ++q) {
                int mt = 2 * w + q;
                s16x8 a1 = *(const s16x8*)&xfrag[((kt * 8 + mt) * 64 + lane) * 8];
                s16x8 a2 = *(const s16x8*)&xfrag[(((4 + kt) * 8 + mt) * 64 + lane) * 8];
                as[q] = MFMA(a1, bsv, as[q]);
                ac[q] = MFMA(a2, bcv, ac[q]);
            }
        }
        int col = lane & 15;
        #pragma unroll
        for (int q = 0; q < 2; ++q)
            #pragma unroll
            for (int i = 0; i < 4; ++i) {
                int p = (2 * w + q) * 16 + ((lane >> 4) << 2) + i;
                if (col == 0)
                    out[6 * NPTS + b * NPTS + n0 + p] = as[q][i] + sb2[0];
                if (col < 3) {
                    float v = ac[q][i] + cb2[col];
                    out[8 * NPTS + (b * 3 + col) * NPTS + n0 + p] =
                        1.f / (1.f + __expf(-v));
                }
            }
    }
}

// ---------------------------------------------------------------------------
extern "C" void kernel_launch(void* const* d_in, const int* in_sizes, int n_in,
                              void* d_out, int out_size, void* d_ws, size_t ws_size,
                              hipStream_t stream) {
    const float* qp   = (const float*)d_in[0];
    const float* qv   = (const float*)d_in[1];
    const float* exp_ = (const float*)d_in[2];
    const float* bs   = (const float*)d_in[3];
    const float* mean = (const float*)d_in[4];
    const float* fvol = (const float*)d_in[5];
    const float* dW1  = (const float*)d_in[6];
    const float* db1  = (const float*)d_in[7];
    const float* dW2  = (const float*)d_in[8];
    const float* db2  = (const float*)d_in[9];
    const float* sW1  = (const float*)d_in[10];
    const float* sb1  = (const float*)d_in[11];
    const float* sW2  = (const float*)d_in[12];
    const float* sb2  = (const float*)d_in[13];
    const float* cW1  = (const float*)d_in[14];
    const float* cb1  = (const float*)d_in[15];
    const float* cW2  = (const float*)d_in[16];
    const float* cb2  = (const float*)d_in[17];

    float* out = (float*)d_out;
    float* ws  = (float*)d_ws;

    float* dvt = ws;                                   // 262144 f
    float* sHb = ws + 262144;                          // 256 f
    float* cHb = ws + 262400;                          // 256 f
    unsigned short* wb = (unsigned short*)(ws + 262656);
    unsigned short* dW1h  = wb;                        // 8192 bf16
    unsigned short* dW1l  = wb + 8192;
    unsigned short* sW1h  = wb + 16384;                // 28672
    unsigned short* sW1l  = wb + 45056;
    unsigned short* cW1f_ = wb + 73728;                // 32768
    unsigned short* dW2f  = wb + 106496;               // 1024
    unsigned short* sW2f  = wb + 107520;               // 2048
    unsigned short* cW2f  = wb + 109568;               // 2048 (ends 111616)
    float* fvt = ws + 318464;                          // 2097152 f
    bool cl = ws_size >= (size_t)(318464 + 2097152) * 4;

    k_deform_vol_t<<<1024, 256, 0, stream>>>(exp_, bs, mean, dvt);
    k_hb<<<2, 128, 0, stream>>>(exp_, sW1, sb1, cW1, cb1, sHb, cHb);
    k_wprep<<<(8192 + 255) / 256, 256, 0, stream>>>(dW1, dW1h, dW1l, 4, 64, 108, 0, 8192);
    k_wprep<<<(28672 + 255) / 256, 256, 0, stream>>>(sW1, sW1h, sW1l, 7, 128, 216, 0, 28672);
    k_wprep<<<(32768 + 255) / 256, 256, 0, stream>>>(cW1, cW1f_, nullptr, 8, 128, 275, 1, 32768);
    k_wprep<<<(1024 + 255) / 256, 256, 0, stream>>>(dW2, dW2f, nullptr, 2, 3, 64, 0, 1024);
    k_wprep<<<(2048 + 255) / 256, 256, 0, stream>>>(sW2, sW2f, nullptr, 4, 1, 128, 0, 2048);
    k_wprep<<<(2048 + 255) / 256, 256, 0, stream>>>(cW2, cW2f, nullptr, 4, 3, 128, 0, 2048);

    if (cl) {
        k_ftr<<<2097152 / 256, 256, 0, stream>>>(fvol, fvt);
        k_main<true><<<4096, 256, 0, stream>>>(
            qp, qv, dvt, fvt, db1, db2, sb2, cb2, sHb, cHb,
            dW1h, dW1l, sW1h, sW1l, cW1f_, dW2f, sW2f, cW2f, out);
    } else {
        k_main<false><<<4096, 256, 0, stream>>>(
            qp, qv, dvt, fvol, db1, db2, sb2, cb2, sHb, cHb,
            dW1h, dW1l, sW1h, sW1l, cW1f_, dW2f, sW2f, cW2f, out);
    }
}

// Round 5
// 318.346 us; speedup vs baseline: 7.0629x; 1.6651x over previous
//
#include <hip/hip_runtime.h>
#include <math.h>

#define NPTS 262144
#define RSTR 130   // raw[] row stride in floats (130%32=2 -> 2-way free aliasing)

typedef __attribute__((ext_vector_type(4))) float f32x4;
typedef __attribute__((ext_vector_type(8))) short s16x8;

// Exact round-to-nearest-even f32->bf16 (matches numpy/JAX). Do NOT use
// v_cvt_pk_bf16_f32: proven non-RTNE by round-3/4 bisection (density fail).
__device__ __forceinline__ unsigned short f2bf(float f) {
    union { float f; unsigned u; } v; v.f = f;
    unsigned u = v.u;
    return (unsigned short)((u + 0x7fffu + ((u >> 16) & 1u)) >> 16);
}
__device__ __forceinline__ float bf2f(unsigned short h) {
    union { unsigned u; float f; } v; v.u = ((unsigned)h) << 16;
    return v.f;
}

// A-fragment address (bf16-element units) for mfma_f32_16x16x32_bf16.
// Lane l holds row p = mt*16 + (l&15), k = kt*32 + 4*(l>>4) + (j&3) + 16*(j>>2).
// xfrag layout: [kt][mt=8][lane=64][j=8].
__device__ __forceinline__ int fragAddr(int p, int k) {
    int kt = k >> 5, kk = k & 31;
    int lane = (((kk & 15) >> 2) << 4) | (p & 15);
    int j = ((kk >> 4) << 2) | (kk & 3);
    int mt = p >> 4;
    return (((kt * 8 + mt) * 64) + lane) * 8 + j;
}

// ---------------------------------------------------------------------------
// deform_vol, channels-last: dvt[b][v][c], v = (z*32+y)*32+x, c<4
// ---------------------------------------------------------------------------
__global__ void k_deform_vol_t(const float* __restrict__ exp_,
                               const float* __restrict__ bs,
                               const float* __restrict__ mean,
                               float* __restrict__ dvt) {
    int idx = blockIdx.x * blockDim.x + threadIdx.x;   // 262144
    int c = idx & 3;
    int v = (idx >> 2) & 32767;
    int b = idx >> 17;
    float acc = mean[c * 32768 + v];
    #pragma unroll 8
    for (int e = 0; e < 32; ++e)
        acc = fmaf(exp_[b * 32 + e], bs[(e * 4 + c) * 32768 + v], acc);
    dvt[idx] = acc;
}

// feature volume transpose: fvt[v][c] = fvol[c][v]
__global__ void k_ftr(const float* __restrict__ fvol, float* __restrict__ fvt) {
    int i = blockIdx.x * blockDim.x + threadIdx.x;     // 2097152
    int c = i >> 18;
    int v = i & 262143;
    fvt[v * 8 + c] = fvol[i];
}

// fold per-batch exp contribution into hidden biases
__global__ void k_hb(const float* __restrict__ exp_,
                     const float* __restrict__ sW1, const float* __restrict__ sb1,
                     const float* __restrict__ cW1, const float* __restrict__ cb1,
                     float* __restrict__ sHb, float* __restrict__ cHb) {
    int b = blockIdx.x;
    int j = threadIdx.x;           // 128
    float a = sb1[j];
    float a2 = cb1[j];
    for (int e = 0; e < 32; ++e) {
        float ev = exp_[b * 32 + e] * (1.0f / 3.0f);
        a  = fmaf(ev, sW1[(216 + e) * 128 + j], a);
        a2 = fmaf(ev, cW1[(243 + e) * 128 + j], a2);
    }
    sHb[b * 128 + j] = a;
    cHb[b * 128 + j] = a2;
}

// ---------------------------------------------------------------------------
// Weight -> B-fragment tables (bf16, optional hi/lo split).
// B frag: lane l holds col n = nt*16 + (l&15), k = kt*32 + 4*(l>>4)+(j&3)+16*(j>>2)
// layout [nt][kt][lane][8].
// K-row mapping:
//  mode 0: identity, row = k < Ksrc ? k : -1
//  mode 1: deform K=128 permuted (validated by output 0):
//          g=k>>5, t=(k>>4)&1, r=k&15
//          r<12 -> 12+24g+12t+r ; else idx=(2g+t)*4+(r-12), idx<12 -> idx
//  mode 2: cW1: k<216 -> k ; 224<=k<251 -> k-8 ; else -1
// ---------------------------------------------------------------------------
__global__ void k_wprep(const float* __restrict__ src,
                        unsigned short* __restrict__ dhi,
                        unsigned short* __restrict__ dlo,
                        int KT, int Nsrc, int Ksrc, int mode, int total) {
    int i = blockIdx.x * 256 + threadIdx.x;
    if (i >= total) return;
    int j = i & 7, lane = (i >> 3) & 63;
    int tile = i >> 9;
    int kt = tile % KT, nt = tile / KT;
    int n = nt * 16 + (lane & 15);
    int k = kt * 32 + ((lane >> 4) << 2) + (j & 3) + ((j >> 2) << 4);
    int row = -1;
    if (mode == 0) {
        row = (k < Ksrc) ? k : -1;
    } else if (mode == 1) {
        int g = k >> 5, tg = (k >> 4) & 1, r = k & 15;
        if (r < 12) row = 12 + 24 * g + 12 * tg + r;
        else { int idx = (2 * g + tg) * 4 + (r - 12); row = (idx < 12) ? idx : -1; }
    } else {
        if (k < 216) row = k;
        else if (k >= 224 && k < 251) row = k - 8;
        else row = -1;
    }
    float v = (row >= 0 && n < Nsrc) ? src[row * Nsrc + n] : 0.0f;
    unsigned short h = f2bf(v);
    dhi[i] = h;
    if (dlo) dlo[i] = f2bf(v - bf2f(h));
}

// ---------------------------------------------------------------------------
// channels-last trilinear gather
// ---------------------------------------------------------------------------
template<int S, int STEP, int DIM, int NC>
__device__ __forceinline__ void lerp_cl(const float* __restrict__ vol,
                                        float px, float py, float pz,
                                        float* __restrict__ o) {
    float fx = px * (float)S - 0.5f;
    float fy = py * (float)S - 0.5f;
    float fz = pz * (float)S - 0.5f;
    float x0 = floorf(fx), y0 = floorf(fy), z0 = floorf(fz);
    float wx = fx - x0, wy = fy - y0, wz = fz - z0;
    int ix = (int)x0, iy = (int)y0, iz = (int)z0;
    #pragma unroll
    for (int c = 0; c < NC; ++c) o[c] = 0.0f;
    #pragma unroll
    for (int dz = 0; dz < 2; ++dz)
    #pragma unroll
    for (int dy = 0; dy < 2; ++dy)
    #pragma unroll
    for (int dx = 0; dx < 2; ++dx) {
        int xi = ix + dx, yi = iy + dy, zi = iz + dz;
        bool valid = (xi >= 0) & (xi < S) & (yi >= 0) & (yi < S) & (zi >= 0) & (zi < S);
        int xc = min(max(xi, 0), S - 1);
        int yc = min(max(yi, 0), S - 1);
        int zc = min(max(zi, 0), S - 1);
        float w = (dz ? wz : 1.f - wz) * (dy ? wy : 1.f - wy) * (dx ? wx : 1.f - wx);
        w = valid ? w : 0.f;
        const float4* q = (const float4*)(vol +
            (size_t)(((zc * STEP) * DIM + yc * STEP) * DIM + xc * STEP) * NC);
        float4 v0 = q[0];
        o[0] = fmaf(v0.x, w, o[0]); o[1] = fmaf(v0.y, w, o[1]);
        o[2] = fmaf(v0.z, w, o[2]); o[3] = fmaf(v0.w, w, o[3]);
        if (NC == 8) {
            float4 v1 = q[1];
            o[4] = fmaf(v1.x, w, o[4]); o[5] = fmaf(v1.y, w, o[5]);
            o[6] = fmaf(v1.z, w, o[6]); o[7] = fmaf(v1.w, w, o[7]);
        }
    }
}

// channel-major fallback
template<int C, int BD, int S, int STEP>
__device__ __forceinline__ void trilerp_cm(const float* __restrict__ vol,
                                           float px, float py, float pz,
                                           float* __restrict__ out) {
    float fx = px * (float)S - 0.5f;
    float fy = py * (float)S - 0.5f;
    float fz = pz * (float)S - 0.5f;
    float x0 = floorf(fx), y0 = floorf(fy), z0 = floorf(fz);
    float wx = fx - x0, wy = fy - y0, wz = fz - z0;
    int ix = (int)x0, iy = (int)y0, iz = (int)z0;
    #pragma unroll
    for (int c = 0; c < C; ++c) out[c] = 0.0f;
    #pragma unroll
    for (int dz = 0; dz < 2; ++dz)
    #pragma unroll
    for (int dy = 0; dy < 2; ++dy)
    #pragma unroll
    for (int dx = 0; dx < 2; ++dx) {
        int xi = ix + dx, yi = iy + dy, zi = iz + dz;
        bool valid = (xi >= 0) & (xi < S) & (yi >= 0) & (yi < S) & (zi >= 0) & (zi < S);
        int xc = min(max(xi, 0), S - 1);
        int yc = min(max(yi, 0), S - 1);
        int zc = min(max(zi, 0), S - 1);
        float w = (dz ? wz : 1.f - wz) * (dy ? wy : 1.f - wy) * (dx ? wx : 1.f - wx);
        w = valid ? w : 0.f;
        int off = ((zc * STEP) * BD + yc * STEP) * BD + xc * STEP;
        #pragma unroll
        for (int c = 0; c < C; ++c)
            out[c] = fmaf(vol[c * (BD * BD * BD) + off], w, out[c]);
    }
}

#define MFMA(a, b, c) __builtin_amdgcn_mfma_f32_16x16x32_bf16((a), (b), (c), 0, 0, 0)

// ---------------------------------------------------------------------------
// Main fused kernel: 128 points / block, 256 threads = 4 waves.
// Feature-path K layout = identity (round-2-proven decode).
// Deform-path K layout = permuted mode 1 (validated by output 0).
// All f32->bf16 via f2bf (RTNE) — cvt_pk_bf16 is NOT RTNE (round-4 lesson).
// ---------------------------------------------------------------------------
template<bool CL>
__global__ __launch_bounds__(256, 2) void k_main(
    const float* __restrict__ qp, const float* __restrict__ qv,
    const float* __restrict__ dvt, const float* __restrict__ fvol,
    const float* __restrict__ db1, const float* __restrict__ db2,
    const float* __restrict__ sb2, const float* __restrict__ cb2,
    const float* __restrict__ sHb, const float* __restrict__ cHb,
    const unsigned short* __restrict__ dW1h, const unsigned short* __restrict__ dW1l,
    const unsigned short* __restrict__ sW1h, const unsigned short* __restrict__ sW1l,
    const unsigned short* __restrict__ cW1f,
    const unsigned short* __restrict__ dW2f, const unsigned short* __restrict__ sW2f,
    const unsigned short* __restrict__ cW2f,
    float* __restrict__ out)
{
    __shared__ __align__(16) unsigned short xfrag[32768];   // 64 KB
    __shared__ __align__(16) float raw[27 * RSTR];           // 13.7 KB
    __shared__ float dp[3 * 128];                            // 1.5 KB

    const int t = threadIdx.x;
    const int lane = t & 63;
    const int w = t >> 6;
    const int gp0 = blockIdx.x * 128;
    const int b = gp0 / NPTS;
    const int n0 = gp0 - b * NPTS;
    const float* qpb = qp + b * 3 * NPTS;
    const float* qvb = qv + b * 3 * NPTS;

    // ---- Phase 1: deform interp -> raw rows 0..11; zero row 12 ----
    {
        const float* dv = dvt + b * 131072;
        for (int task = t; task < 384; task += 256) {
            int p = task & 127, lvl = task >> 7;
            int n = n0 + p;
            float px = qpb[n], py = qpb[NPTS + n], pz = qpb[2 * NPTS + n];
            float o[4];
            if (lvl == 0)      lerp_cl<32, 1, 32, 4>(dv, px, py, pz, o);
            else if (lvl == 1) lerp_cl<16, 2, 32, 4>(dv, px, py, pz, o);
            else               lerp_cl< 8, 4, 32, 4>(dv, px, py, pz, o);
            #pragma unroll
            for (int c = 0; c < 4; ++c) raw[(lvl * 4 + c) * RSTR + p] = o[c];
        }
        if (t < 128) raw[12 * RSTR + t] = 0.f;
    }
    __syncthreads();

    // ---- Phase 2: embed deform -> X_d frags (K=128, kt 0..3, mode-1 layout) --
    {
        #pragma unroll
        for (int i = 0; i < 8; ++i) {
            const int kt = i >> 1;
            const int g = kt;
            const float sc = (float)(1 << g);
            int mt = (i * 4 + w) & 7;
            int p = mt * 16 + (lane & 15);
            int c = (lane >> 4) << 2;
            float vs[8];
            #pragma unroll
            for (int m = 0; m < 4; ++m) {
                int r = c + m;
                bool scs = r < 12;
                int i0 = 8 * g + (r - 12);
                int i1 = i0 + 4;
                int row0 = scs ? r : (i0 < 12 ? i0 : 12);
                int row1 = scs ? r : (i1 < 12 ? i1 : 12);
                float v0 = raw[row0 * RSTR + p];
                float v1 = raw[row1 * RSTR + p];
                float x = v0 * sc;
                vs[m]     = scs ? __sinf(x) : v0;   // j 0..3: trig bit 0 (sin)
                vs[4 + m] = scs ? __cosf(x) : v1;   // j 4..7: trig bit 1 (cos)
            }
            union { unsigned short s[8]; s16x8 v; } pk;
            #pragma unroll
            for (int m = 0; m < 8; ++m) pk.s[m] = f2bf(vs[m]);
            *(s16x8*)&xfrag[(((kt * 8 + mt) * 64) + lane) * 8] = pk.v;
        }
    }
    __syncthreads();

    // ---- Phase 3: dMLP layer1 (K=128, N=64; wave w -> nt=w; hi/lo split) ----
    {
        f32x4 acc[8];
        float bias = db1[w * 16 + (lane & 15)];
        #pragma unroll
        for (int mt = 0; mt < 8; ++mt) acc[mt] = (f32x4){bias, bias, bias, bias};
        #pragma unroll 1
        for (int kt = 0; kt < 4; ++kt) {
            s16x8 bh = *(const s16x8*)&dW1h[((w * 4 + kt) * 64 + lane) * 8];
            s16x8 bl = *(const s16x8*)&dW1l[((w * 4 + kt) * 64 + lane) * 8];
            #pragma unroll
            for (int mt = 0; mt < 8; ++mt) {
                s16x8 a = *(const s16x8*)&xfrag[((kt * 8 + mt) * 64 + lane) * 8];
                acc[mt] = MFMA(a, bh, acc[mt]);
                acc[mt] = MFMA(a, bl, acc[mt]);
            }
        }
        // relu -> H_d frags at k = 128 + j (kt 4..5), identity mapping
        int j = w * 16 + (lane & 15);
        #pragma unroll
        for (int mt = 0; mt < 8; ++mt)
            #pragma unroll
            for (int i = 0; i < 4; ++i) {
                int p = mt * 16 + ((lane >> 4) << 2) + i;
                xfrag[fragAddr(p, 128 + j)] = f2bf(fmaxf(acc[mt][i], 0.f));
            }
    }
    __syncthreads();

    // ---- Phase 4: dMLP layer2 (K=64; wave w -> mt {2w,2w+1}) ----
    {
        f32x4 acc[2] = {(f32x4){0,0,0,0}, (f32x4){0,0,0,0}};
        #pragma unroll
        for (int kt = 0; kt < 2; ++kt) {
            s16x8 bb = *(const s16x8*)&dW2f[(kt * 64 + lane) * 8];
            #pragma unroll
            for (int q = 0; q < 2; ++q) {
                int mt = 2 * w + q;
                s16x8 a = *(const s16x8*)&xfrag[(((4 + kt) * 8 + mt) * 64 + lane) * 8];
                acc[q] = MFMA(a, bb, acc[q]);
            }
        }
        int col = lane & 15;
        if (col < 3) {
            #pragma unroll
            for (int q = 0; q < 2; ++q)
                #pragma unroll
                for (int i = 0; i < 4; ++i) {
                    int p = (2 * w + q) * 16 + ((lane >> 4) << 2) + i;
                    float v = acc[q][i] + db2[col];
                    out[(b * 3 + col) * NPTS + n0 + p] = v;
                    dp[col * 128 + p] = fmaf(v, 0.1f, qpb[col * NPTS + n0 + p]);
                }
        }
    }
    __syncthreads();

    // ---- Phase 5: feature interp -> raw 0..23; viewdir -> rows 24..26 ----
    {
        for (int task = t; task < 384; task += 256) {
            int p = task & 127, lvl = task >> 7;
            float px = dp[p], py = dp[128 + p], pz = dp[256 + p];
            float o[8];
            if (CL) {
                if (lvl == 0)      lerp_cl<64, 1, 64, 8>(fvol, px, py, pz, o);
                else if (lvl == 1) lerp_cl<32, 2, 64, 8>(fvol, px, py, pz, o);
                else               lerp_cl<16, 4, 64, 8>(fvol, px, py, pz, o);
            } else {
                if (lvl == 0)      trilerp_cm<8, 64, 64, 1>(fvol, px, py, pz, o);
                else if (lvl == 1) trilerp_cm<8, 64, 32, 2>(fvol, px, py, pz, o);
                else               trilerp_cm<8, 64, 16, 4>(fvol, px, py, pz, o);
            }
            #pragma unroll
            for (int c = 0; c < 8; ++c) raw[(lvl * 8 + c) * RSTR + p] = o[c];
        }
        if (t < 128) {
            int n = n0 + t;
            raw[24 * RSTR + t] = qvb[n];
            raw[25 * RSTR + t] = qvb[NPTS + n];
            raw[26 * RSTR + t] = qvb[2 * NPTS + n];
        }
    }
    __syncthreads();

    // ---- Phase 6: embed feature+view -> X frags (K=256, identity layout) ----
    {
        #pragma unroll
        for (int i = 0; i < 16; ++i) {
            const int kt = i >> 1;
            int mt = (i * 4 + w) & 7;
            int p = mt * 16 + (lane & 15);
            int K0 = kt * 32 + ((lane >> 4) << 2);
            float vs[8];
            #pragma unroll
            for (int m = 0; m < 8; ++m) {
                int k = K0 + (m & 3) + ((m >> 2) << 4);
                float val;
                if (k < 24) {
                    val = raw[k * RSTR + p];
                } else if (k < 216) {
                    int u = k - 24;
                    int g = u / 48;
                    int r = u - 48 * g;
                    float sc = (float)(1 << g);
                    int rr = (r < 24) ? r : r - 24;
                    float x = raw[rr * RSTR + p] * sc;
                    val = (r < 24) ? __sinf(x) : __cosf(x);
                } else if (k < 224) {
                    val = 0.f;
                } else if (k < 251) {
                    int idx = k - 224;
                    if (idx < 3) val = raw[(24 + idx) * RSTR + p];
                    else {
                        int u2 = idx - 3;
                        int g2 = u2 / 6;
                        int r2 = u2 - 6 * g2;
                        float sc2 = (float)(1 << g2);
                        int rr2 = (r2 < 3) ? r2 : r2 - 3;
                        float x2 = raw[(24 + rr2) * RSTR + p] * sc2;
                        val = (r2 < 3) ? __sinf(x2) : __cosf(x2);
                    }
                } else {
                    val = 0.f;
                }
                vs[m] = val;
            }
            union { unsigned short s[8]; s16x8 v; } pk;
            #pragma unroll
            for (int m = 0; m < 8; ++m) pk.s[m] = f2bf(vs[m]);
            *(s16x8*)&xfrag[(((kt * 8 + mt) * 64) + lane) * 8] = pk.v;
        }
    }
    __syncthreads();

    // ---- Phase 7: density L1 (K=224 -> kt<7, hi/lo) + color L1 (K=256) ----
    f32x4 accs[8][2], accc[8][2];
    {
        int nl = lane & 15;
        #pragma unroll
        for (int q = 0; q < 2; ++q) {
            float bsv = sHb[b * 128 + (2 * w + q) * 16 + nl];
            float bcv = cHb[b * 128 + (2 * w + q) * 16 + nl];
            #pragma unroll
            for (int mt = 0; mt < 8; ++mt) {
                accs[mt][q] = (f32x4){bsv, bsv, bsv, bsv};
                accc[mt][q] = (f32x4){bcv, bcv, bcv, bcv};
            }
        }
        #pragma unroll 1
        for (int kt = 0; kt < 7; ++kt) {
            s16x8 bh0 = *(const s16x8*)&sW1h[(((2 * w    ) * 8 + kt) * 64 + lane) * 8];
            s16x8 bl0 = *(const s16x8*)&sW1l[(((2 * w    ) * 8 + kt) * 64 + lane) * 8];
            s16x8 bh1 = *(const s16x8*)&sW1h[(((2 * w + 1) * 8 + kt) * 64 + lane) * 8];
            s16x8 bl1 = *(const s16x8*)&sW1l[(((2 * w + 1) * 8 + kt) * 64 + lane) * 8];
            #pragma unroll
            for (int mt = 0; mt < 8; ++mt) {
                s16x8 a = *(const s16x8*)&xfrag[((kt * 8 + mt) * 64 + lane) * 8];
                accs[mt][0] = MFMA(a, bh0, accs[mt][0]);
                accs[mt][0] = MFMA(a, bl0, accs[mt][0]);
                accs[mt][1] = MFMA(a, bh1, accs[mt][1]);
                accs[mt][1] = MFMA(a, bl1, accs[mt][1]);
            }
        }
        #pragma unroll 1
        for (int kt = 0; kt < 8; ++kt) {
            s16x8 b0 = *(const s16x8*)&cW1f[(((2 * w    ) * 8 + kt) * 64 + lane) * 8];
            s16x8 b1 = *(const s16x8*)&cW1f[(((2 * w + 1) * 8 + kt) * 64 + lane) * 8];
            #pragma unroll
            for (int mt = 0; mt < 8; ++mt) {
                s16x8 a = *(const s16x8*)&xfrag[((kt * 8 + mt) * 64 + lane) * 8];
                accc[mt][0] = MFMA(a, b0, accc[mt][0]);
                accc[mt][1] = MFMA(a, b1, accc[mt][1]);
            }
        }
    }
    __syncthreads();

    // ---- Phase 8: relu -> H_s frags (kt 0..3), H_c frags (kt 4..7) ----
    {
        #pragma unroll
        for (int q = 0; q < 2; ++q) {
            int j = (2 * w + q) * 16 + (lane & 15);
            #pragma unroll
            for (int mt = 0; mt < 8; ++mt)
                #pragma unroll
                for (int i = 0; i < 4; ++i) {
                    int p = mt * 16 + ((lane >> 4) << 2) + i;
                    xfrag[fragAddr(p, j)]       = f2bf(fmaxf(accs[mt][q][i], 0.f));
                    xfrag[fragAddr(p, 128 + j)] = f2bf(fmaxf(accc[mt][q][i], 0.f));
                }
        }
    }
    __syncthreads();

    // ---- Phase 9: density L2 + color L2 (K=128 each) ----
    {
        f32x4 as[2] = {(f32x4){0,0,0,0}, (f32x4){0,0,0,0}};
        f32x4 ac[2] = {(f32x4){0,0,0,0}, (f32x4){0,0,0,0}};
        #pragma unroll
        for (int kt = 0; kt < 4; ++kt) {
            s16x8 bsv = *(const s16x8*)&sW2f[(kt * 64 + lane) * 8];
            s16x8 bcv = *(const s16x8*)&cW2f[(kt * 64 + lane) * 8];
            #pragma unroll
            for (int q = 0; q < 2; ++q) {
                int mt = 2 * w + q;
                s16x8 a1 = *(const s16x8*)&xfrag[((kt * 8 + mt) * 64 + lane) * 8];
                s16x8 a2 = *(const s16x8*)&xfrag[(((4 + kt) * 8 + mt) * 64 + lane) * 8];
                as[q] = MFMA(a1, bsv, as[q]);
                ac[q] = MFMA(a2, bcv, ac[q]);
            }
        }
        int col = lane & 15;
        #pragma unroll
        for (int q = 0; q < 2; ++q)
            #pragma unroll
            for (int i = 0; i < 4; ++i) {
                int p = (2 * w + q) * 16 + ((lane >> 4) << 2) + i;
                if (col == 0)
                    out[6 * NPTS + b * NPTS + n0 + p] = as[q][i] + sb2[0];
                if (col < 3) {
                    float v = ac[q][i] + cb2[col];
                    out[8 * NPTS + (b * 3 + col) * NPTS + n0 + p] =
                        1.f / (1.f + __expf(-v));
                }
            }
    }
}

// ---------------------------------------------------------------------------
extern "C" void kernel_launch(void* const* d_in, const int* in_sizes, int n_in,
                              void* d_out, int out_size, void* d_ws, size_t ws_size,
                              hipStream_t stream) {
    const float* qp   = (const float*)d_in[0];
    const float* qv   = (const float*)d_in[1];
    const float* exp_ = (const float*)d_in[2];
    const float* bs   = (const float*)d_in[3];
    const float* mean = (const float*)d_in[4];
    const float* fvol = (const float*)d_in[5];
    const float* dW1  = (const float*)d_in[6];
    const float* db1  = (const float*)d_in[7];
    const float* dW2  = (const float*)d_in[8];
    const float* db2  = (const float*)d_in[9];
    const float* sW1  = (const float*)d_in[10];
    const float* sb1  = (const float*)d_in[11];
    const float* sW2  = (const float*)d_in[12];
    const float* sb2  = (const float*)d_in[13];
    const float* cW1  = (const float*)d_in[14];
    const float* cb1  = (const float*)d_in[15];
    const float* cW2  = (const float*)d_in[16];
    const float* cb2  = (const float*)d_in[17];

    float* out = (float*)d_out;
    float* ws  = (float*)d_ws;

    float* dvt = ws;                                   // 262144 f
    float* sHb = ws + 262144;                          // 256 f
    float* cHb = ws + 262400;                          // 256 f
    unsigned short* wb = (unsigned short*)(ws + 262656);
    unsigned short* dW1h  = wb;                        // 8192
    unsigned short* dW1l  = wb + 8192;                 // 8192
    unsigned short* sW1h  = wb + 16384;                // 32768
    unsigned short* sW1l  = wb + 49152;                // 32768
    unsigned short* cW1f_ = wb + 81920;                // 32768
    unsigned short* dW2f  = wb + 114688;               // 1024
    unsigned short* sW2f  = wb + 115712;               // 2048
    unsigned short* cW2f  = wb + 117760;               // 2048 (end 119808 u16)
    float* fvt = ws + 262656 + 59904;                  // = ws + 322560
    bool cl = ws_size >= (size_t)(322560 + 2097152) * 4;

    k_deform_vol_t<<<1024, 256, 0, stream>>>(exp_, bs, mean, dvt);
    k_hb<<<2, 128, 0, stream>>>(exp_, sW1, sb1, cW1, cb1, sHb, cHb);
    k_wprep<<<32, 256, 0, stream>>>(dW1, dW1h, dW1l, 4, 64, 128, 1, 8192);
    k_wprep<<<128, 256, 0, stream>>>(sW1, sW1h, sW1l, 8, 128, 216, 0, 32768);
    k_wprep<<<128, 256, 0, stream>>>(cW1, cW1f_, nullptr, 8, 128, 275, 2, 32768);
    k_wprep<<<4, 256, 0, stream>>>(dW2, dW2f, nullptr, 2, 3, 64, 0, 1024);
    k_wprep<<<8, 256, 0, stream>>>(sW2, sW2f, nullptr, 4, 1, 128, 0, 2048);
    k_wprep<<<8, 256, 0, stream>>>(cW2, cW2f, nullptr, 4, 3, 128, 0, 2048);

    if (cl) {
        k_ftr<<<2097152 / 256, 256, 0, stream>>>(fvol, fvt);
        k_main<true><<<4096, 256, 0, stream>>>(
            qp, qv, dvt, fvt, db1, db2, sb2, cb2, sHb, cHb,
            dW1h, dW1l, sW1h, sW1l, cW1f_, dW2f, sW2f, cW2f, out);
    } else {
        k_main<false><<<4096, 256, 0, stream>>>(
            qp, qv, dvt, fvol, db1, db2, sb2, cb2, sHb, cHb,
            dW1h, dW1l, sW1h, sW1l, cW1f_, dW2f, sW2f, cW2f, out);
    }
}

// Round 6
// 277.329 us; speedup vs baseline: 8.1075x; 1.1479x over previous
//
#include <hip/hip_runtime.h>
#include <math.h>

#define NPTS 262144
#define RSTR 66    // raw[] row stride in floats (64 pts + 2 pad)

typedef __attribute__((ext_vector_type(4))) float f32x4;
typedef __attribute__((ext_vector_type(8))) short s16x8;

// Exact round-to-nearest-even f32->bf16 (matches numpy/JAX). Do NOT use
// v_cvt_pk_bf16_f32: proven non-RTNE by round-3/4 bisection (density fail).
__device__ __forceinline__ unsigned short f2bf(float f) {
    union { float f; unsigned u; } v; v.f = f;
    unsigned u = v.u;
    return (unsigned short)((u + 0x7fffu + ((u >> 16) & 1u)) >> 16);
}
__device__ __forceinline__ float bf2f(unsigned short h) {
    union { unsigned u; float f; } v; v.u = ((unsigned)h) << 16;
    return v.f;
}

// xfrag element-address swizzle: inject lane'[4],lane'[5] (bits 7,8) into
// bank bits 3,4. Only bits >=3 touched -> 16B granules permuted, b128-safe.
// Applied to EVERY xfrag access (stores and loads) -> pure bijection.
__device__ __forceinline__ int swz(int e) {
    return e ^ (((e >> 7) & 1) << 3) ^ (((e >> 8) & 1) << 4);
}

// Linear fragment base (bf16-element units): [kt][mt=4][lane=64][j=8]
__device__ __forceinline__ int XF(int kt, int mt, int lane) {
    return ((kt * 4 + mt) * 64 + lane) * 8;
}

// A-fragment scatter address (swizzled) for mfma_f32_16x16x32_bf16.
// Lane l holds row p = mt*16 + (l&15), k = kt*32 + 4*(l>>4) + (j&3) + 16*(j>>2).
__device__ __forceinline__ int fragAddr(int p, int k) {
    int kt = k >> 5, kk = k & 31;
    int lane = (((kk & 15) >> 2) << 4) | (p & 15);
    int j = ((kk >> 4) << 2) | (kk & 3);
    int mt = (p >> 4) & 3;
    return swz((((kt * 4 + mt) * 64) + lane) * 8 + j);
}

// ---------------------------------------------------------------------------
// deform_vol, channels-last: dvt[b][v][c], v = (z*32+y)*32+x, c<4
// ---------------------------------------------------------------------------
__global__ void k_deform_vol_t(const float* __restrict__ exp_,
                               const float* __restrict__ bs,
                               const float* __restrict__ mean,
                               float* __restrict__ dvt) {
    int idx = blockIdx.x * blockDim.x + threadIdx.x;   // 262144
    int c = idx & 3;
    int v = (idx >> 2) & 32767;
    int b = idx >> 17;
    float acc = mean[c * 32768 + v];
    #pragma unroll 8
    for (int e = 0; e < 32; ++e)
        acc = fmaf(exp_[b * 32 + e], bs[(e * 4 + c) * 32768 + v], acc);
    dvt[idx] = acc;
}

// feature volume transpose: fvt[v][c] = fvol[c][v]
__global__ void k_ftr(const float* __restrict__ fvol, float* __restrict__ fvt) {
    int i = blockIdx.x * blockDim.x + threadIdx.x;     // 2097152
    int c = i >> 18;
    int v = i & 262143;
    fvt[v * 8 + c] = fvol[i];
}

// fold per-batch exp contribution into hidden biases
__global__ void k_hb(const float* __restrict__ exp_,
                     const float* __restrict__ sW1, const float* __restrict__ sb1,
                     const float* __restrict__ cW1, const float* __restrict__ cb1,
                     float* __restrict__ sHb, float* __restrict__ cHb) {
    int b = blockIdx.x;
    int j = threadIdx.x;           // 128
    float a = sb1[j];
    float a2 = cb1[j];
    for (int e = 0; e < 32; ++e) {
        float ev = exp_[b * 32 + e] * (1.0f / 3.0f);
        a  = fmaf(ev, sW1[(216 + e) * 128 + j], a);
        a2 = fmaf(ev, cW1[(243 + e) * 128 + j], a2);
    }
    sHb[b * 128 + j] = a;
    cHb[b * 128 + j] = a2;
}

// ---------------------------------------------------------------------------
// Weight -> B-fragment tables (bf16, optional hi/lo split).
// B frag: lane l holds col n = nt*16 + (l&15), k = kt*32 + 4*(l>>4)+(j&3)+16*(j>>2)
// layout [nt][kt][lane][8].
// K-row mapping:
//  mode 0: identity, row = k < Ksrc ? k : -1
//  mode 1: deform K=128 permuted (validated):
//          g=k>>5, t=(k>>4)&1, r=k&15
//          r<12 -> 12+24g+12t+r ; else idx=(2g+t)*4+(r-12), idx<12 -> idx
//  mode 2: cW1: k<216 -> k ; 224<=k<251 -> k-8 ; else -1
// ---------------------------------------------------------------------------
__global__ void k_wprep(const float* __restrict__ src,
                        unsigned short* __restrict__ dhi,
                        unsigned short* __restrict__ dlo,
                        int KT, int Nsrc, int Ksrc, int mode, int total) {
    int i = blockIdx.x * 256 + threadIdx.x;
    if (i >= total) return;
    int j = i & 7, lane = (i >> 3) & 63;
    int tile = i >> 9;
    int kt = tile % KT, nt = tile / KT;
    int n = nt * 16 + (lane & 15);
    int k = kt * 32 + ((lane >> 4) << 2) + (j & 3) + ((j >> 2) << 4);
    int row = -1;
    if (mode == 0) {
        row = (k < Ksrc) ? k : -1;
    } else if (mode == 1) {
        int g = k >> 5, tg = (k >> 4) & 1, r = k & 15;
        if (r < 12) row = 12 + 24 * g + 12 * tg + r;
        else { int idx = (2 * g + tg) * 4 + (r - 12); row = (idx < 12) ? idx : -1; }
    } else {
        if (k < 216) row = k;
        else if (k >= 224 && k < 251) row = k - 8;
        else row = -1;
    }
    float v = (row >= 0 && n < Nsrc) ? src[row * Nsrc + n] : 0.0f;
    unsigned short h = f2bf(v);
    dhi[i] = h;
    if (dlo) dlo[i] = f2bf(v - bf2f(h));
}

// ---------------------------------------------------------------------------
// channels-last trilinear gather
// ---------------------------------------------------------------------------
template<int S, int STEP, int DIM, int NC>
__device__ __forceinline__ void lerp_cl(const float* __restrict__ vol,
                                        float px, float py, float pz,
                                        float* __restrict__ o) {
    float fx = px * (float)S - 0.5f;
    float fy = py * (float)S - 0.5f;
    float fz = pz * (float)S - 0.5f;
    float x0 = floorf(fx), y0 = floorf(fy), z0 = floorf(fz);
    float wx = fx - x0, wy = fy - y0, wz = fz - z0;
    int ix = (int)x0, iy = (int)y0, iz = (int)z0;
    #pragma unroll
    for (int c = 0; c < NC; ++c) o[c] = 0.0f;
    #pragma unroll
    for (int dz = 0; dz < 2; ++dz)
    #pragma unroll
    for (int dy = 0; dy < 2; ++dy)
    #pragma unroll
    for (int dx = 0; dx < 2; ++dx) {
        int xi = ix + dx, yi = iy + dy, zi = iz + dz;
        bool valid = (xi >= 0) & (xi < S) & (yi >= 0) & (yi < S) & (zi >= 0) & (zi < S);
        int xc = min(max(xi, 0), S - 1);
        int yc = min(max(yi, 0), S - 1);
        int zc = min(max(zi, 0), S - 1);
        float w = (dz ? wz : 1.f - wz) * (dy ? wy : 1.f - wy) * (dx ? wx : 1.f - wx);
        w = valid ? w : 0.f;
        const float4* q = (const float4*)(vol +
            (size_t)(((zc * STEP) * DIM + yc * STEP) * DIM + xc * STEP) * NC);
        float4 v0 = q[0];
        o[0] = fmaf(v0.x, w, o[0]); o[1] = fmaf(v0.y, w, o[1]);
        o[2] = fmaf(v0.z, w, o[2]); o[3] = fmaf(v0.w, w, o[3]);
        if (NC == 8) {
            float4 v1 = q[1];
            o[4] = fmaf(v1.x, w, o[4]); o[5] = fmaf(v1.y, w, o[5]);
            o[6] = fmaf(v1.z, w, o[6]); o[7] = fmaf(v1.w, w, o[7]);
        }
    }
}

// channel-major fallback
template<int C, int BD, int S, int STEP>
__device__ __forceinline__ void trilerp_cm(const float* __restrict__ vol,
                                           float px, float py, float pz,
                                           float* __restrict__ out) {
    float fx = px * (float)S - 0.5f;
    float fy = py * (float)S - 0.5f;
    float fz = pz * (float)S - 0.5f;
    float x0 = floorf(fx), y0 = floorf(fy), z0 = floorf(fz);
    float wx = fx - x0, wy = fy - y0, wz = fz - z0;
    int ix = (int)x0, iy = (int)y0, iz = (int)z0;
    #pragma unroll
    for (int c = 0; c < C; ++c) out[c] = 0.0f;
    #pragma unroll
    for (int dz = 0; dz < 2; ++dz)
    #pragma unroll
    for (int dy = 0; dy < 2; ++dy)
    #pragma unroll
    for (int dx = 0; dx < 2; ++dx) {
        int xi = ix + dx, yi = iy + dy, zi = iz + dz;
        bool valid = (xi >= 0) & (xi < S) & (yi >= 0) & (yi < S) & (zi >= 0) & (zi < S);
        int xc = min(max(xi, 0), S - 1);
        int yc = min(max(yi, 0), S - 1);
        int zc = min(max(zi, 0), S - 1);
        float w = (dz ? wz : 1.f - wz) * (dy ? wy : 1.f - wy) * (dx ? wx : 1.f - wx);
        w = valid ? w : 0.f;
        int off = ((zc * STEP) * BD + yc * STEP) * BD + xc * STEP;
        #pragma unroll
        for (int c = 0; c < C; ++c)
            out[c] = fmaf(vol[c * (BD * BD * BD) + off], w, out[c]);
    }
}

#define MFMA(a, b, c) __builtin_amdgcn_mfma_f32_16x16x32_bf16((a), (b), (c), 0, 0, 0)

// ---------------------------------------------------------------------------
// Main fused kernel: 64 points / block, 256 threads = 4 waves, 4 blocks/CU.
// xfrag: [kt 0..7][mt 0..3][lane][8] bf16, swizzled addressing (swz).
// Feature-path K layout = identity (round-2/5-proven decode).
// Deform-path K layout = permuted mode 1 (validated).
// All f32->bf16 via f2bf (RTNE) — cvt_pk_bf16 is NOT RTNE (round-4 lesson).
// ---------------------------------------------------------------------------
template<bool CL>
__global__ __launch_bounds__(256, 4) void k_main(
    const float* __restrict__ qp, const float* __restrict__ qv,
    const float* __restrict__ dvt, const float* __restrict__ fvol,
    const float* __restrict__ db1, const float* __restrict__ db2,
    const float* __restrict__ sb2, const float* __restrict__ cb2,
    const float* __restrict__ sHb, const float* __restrict__ cHb,
    const unsigned short* __restrict__ dW1h, const unsigned short* __restrict__ dW1l,
    const unsigned short* __restrict__ sW1h, const unsigned short* __restrict__ sW1l,
    const unsigned short* __restrict__ cW1f,
    const unsigned short* __restrict__ dW2f, const unsigned short* __restrict__ sW2f,
    const unsigned short* __restrict__ cW2f,
    float* __restrict__ out)
{
    __shared__ __align__(16) unsigned short xfrag[16384];    // 32 KB
    __shared__ __align__(16) float raw[27 * RSTR];           // 7.1 KB
    __shared__ float dp[3 * 64];                             // 0.75 KB

    const int t = threadIdx.x;
    const int lane = t & 63;
    const int w = t >> 6;
    const int gp0 = blockIdx.x * 64;
    const int b = gp0 / NPTS;
    const int n0 = gp0 - b * NPTS;
    const float* qpb = qp + b * 3 * NPTS;
    const float* qvb = qv + b * 3 * NPTS;

    // ---- Phase 1: deform interp -> raw rows 0..11; zero row 12 ----
    {
        const float* dv = dvt + b * 131072;
        if (t < 192) {
            int p = t & 63, lvl = t >> 6;
            int n = n0 + p;
            float px = qpb[n], py = qpb[NPTS + n], pz = qpb[2 * NPTS + n];
            float o[4];
            if (lvl == 0)      lerp_cl<32, 1, 32, 4>(dv, px, py, pz, o);
            else if (lvl == 1) lerp_cl<16, 2, 32, 4>(dv, px, py, pz, o);
            else               lerp_cl< 8, 4, 32, 4>(dv, px, py, pz, o);
            #pragma unroll
            for (int c = 0; c < 4; ++c) raw[(lvl * 4 + c) * RSTR + p] = o[c];
        }
        if (t < 64) raw[12 * RSTR + t] = 0.f;
    }
    __syncthreads();

    // ---- Phase 2: embed deform -> X_d frags (K=128, kt 0..3, mode-1 layout) --
    {
        #pragma unroll
        for (int kt = 0; kt < 4; ++kt) {
            const int g = kt;
            const float sc = (float)(1 << g);
            int mt = w;
            int p = mt * 16 + (lane & 15);
            int c = (lane >> 4) << 2;
            float vs[8];
            #pragma unroll
            for (int m = 0; m < 4; ++m) {
                int r = c + m;
                bool scs = r < 12;
                int i0 = 8 * g + (r - 12);
                int i1 = i0 + 4;
                int row0 = scs ? r : (i0 < 12 ? i0 : 12);
                int row1 = scs ? r : (i1 < 12 ? i1 : 12);
                float v0 = raw[row0 * RSTR + p];
                float v1 = raw[row1 * RSTR + p];
                float x = v0 * sc;
                vs[m]     = scs ? __sinf(x) : v0;   // j 0..3: sin half
                vs[4 + m] = scs ? __cosf(x) : v1;   // j 4..7: cos half
            }
            union { unsigned short s[8]; s16x8 v; } pk;
            #pragma unroll
            for (int m = 0; m < 8; ++m) pk.s[m] = f2bf(vs[m]);
            *(s16x8*)&xfrag[swz(XF(kt, mt, lane))] = pk.v;
        }
    }
    __syncthreads();

    // ---- Phase 3: dMLP layer1 (K=128, N=64; wave w -> nt=w; hi/lo split) ----
    {
        f32x4 acc[4];
        float bias = db1[w * 16 + (lane & 15)];
        #pragma unroll
        for (int mt = 0; mt < 4; ++mt) acc[mt] = (f32x4){bias, bias, bias, bias};
        #pragma unroll 1
        for (int kt = 0; kt < 4; ++kt) {
            s16x8 bh = *(const s16x8*)&dW1h[((w * 4 + kt) * 64 + lane) * 8];
            s16x8 bl = *(const s16x8*)&dW1l[((w * 4 + kt) * 64 + lane) * 8];
            #pragma unroll
            for (int mt = 0; mt < 4; ++mt) {
                s16x8 a = *(const s16x8*)&xfrag[swz(XF(kt, mt, lane))];
                acc[mt] = MFMA(a, bh, acc[mt]);
                acc[mt] = MFMA(a, bl, acc[mt]);
            }
        }
        // relu -> H_d frags at k = 128 + j (kt 4..5), identity mapping
        int j = w * 16 + (lane & 15);
        #pragma unroll
        for (int mt = 0; mt < 4; ++mt)
            #pragma unroll
            for (int i = 0; i < 4; ++i) {
                int p = mt * 16 + ((lane >> 4) << 2) + i;
                xfrag[fragAddr(p, 128 + j)] = f2bf(fmaxf(acc[mt][i], 0.f));
            }
    }
    __syncthreads();

    // ---- Phase 4: dMLP layer2 (K=64; wave w -> mt=w) ----
    {
        f32x4 acc = (f32x4){0, 0, 0, 0};
        #pragma unroll
        for (int kt = 0; kt < 2; ++kt) {
            s16x8 bb = *(const s16x8*)&dW2f[(kt * 64 + lane) * 8];
            s16x8 a = *(const s16x8*)&xfrag[swz(XF(4 + kt, w, lane))];
            acc = MFMA(a, bb, acc);
        }
        int col = lane & 15;
        if (col < 3) {
            #pragma unroll
            for (int i = 0; i < 4; ++i) {
                int p = w * 16 + ((lane >> 4) << 2) + i;
                float v = acc[i] + db2[col];
                out[(b * 3 + col) * NPTS + n0 + p] = v;
                dp[col * 64 + p] = fmaf(v, 0.1f, qpb[col * NPTS + n0 + p]);
            }
        }
    }
    __syncthreads();

    // ---- Phase 5: feature interp -> raw 0..23; viewdir -> rows 24..26 ----
    {
        if (t < 192) {
            int p = t & 63, lvl = t >> 6;
            float px = dp[p], py = dp[64 + p], pz = dp[128 + p];
            float o[8];
            if (CL) {
                if (lvl == 0)      lerp_cl<64, 1, 64, 8>(fvol, px, py, pz, o);
                else if (lvl == 1) lerp_cl<32, 2, 64, 8>(fvol, px, py, pz, o);
                else               lerp_cl<16, 4, 64, 8>(fvol, px, py, pz, o);
            } else {
                if (lvl == 0)      trilerp_cm<8, 64, 64, 1>(fvol, px, py, pz, o);
                else if (lvl == 1) trilerp_cm<8, 64, 32, 2>(fvol, px, py, pz, o);
                else               trilerp_cm<8, 64, 16, 4>(fvol, px, py, pz, o);
            }
            #pragma unroll
            for (int c = 0; c < 8; ++c) raw[(lvl * 8 + c) * RSTR + p] = o[c];
        }
        if (t < 64) {
            int n = n0 + t;
            raw[24 * RSTR + t] = qvb[n];
            raw[25 * RSTR + t] = qvb[NPTS + n];
            raw[26 * RSTR + t] = qvb[2 * NPTS + n];
        }
    }
    __syncthreads();

    // ---- Phase 6: embed feature+view -> X frags (K=256, identity layout) ----
    {
        #pragma unroll
        for (int kt = 0; kt < 8; ++kt) {
            int mt = w;
            int p = mt * 16 + (lane & 15);
            int K0 = kt * 32 + ((lane >> 4) << 2);
            float vs[8];
            #pragma unroll
            for (int m = 0; m < 8; ++m) {
                int k = K0 + (m & 3) + ((m >> 2) << 4);
                float val;
                if (k < 24) {
                    val = raw[k * RSTR + p];
                } else if (k < 216) {
                    int u = k - 24;
                    int g = u / 48;
                    int r = u - 48 * g;
                    float sc = (float)(1 << g);
                    int rr = (r < 24) ? r : r - 24;
                    float x = raw[rr * RSTR + p] * sc;
                    val = (r < 24) ? __sinf(x) : __cosf(x);
                } else if (k < 224) {
                    val = 0.f;
                } else if (k < 251) {
                    int idx = k - 224;
                    if (idx < 3) val = raw[(24 + idx) * RSTR + p];
                    else {
                        int u2 = idx - 3;
                        int g2 = u2 / 6;
                        int r2 = u2 - 6 * g2;
                        float sc2 = (float)(1 << g2);
                        int rr2 = (r2 < 3) ? r2 : r2 - 3;
                        float x2 = raw[(24 + rr2) * RSTR + p] * sc2;
                        val = (r2 < 3) ? __sinf(x2) : __cosf(x2);
                    }
                } else {
                    val = 0.f;
                }
                vs[m] = val;
            }
            union { unsigned short s[8]; s16x8 v; } pk;
            #pragma unroll
            for (int m = 0; m < 8; ++m) pk.s[m] = f2bf(vs[m]);
            *(s16x8*)&xfrag[swz(XF(kt, mt, lane))] = pk.v;
        }
    }
    __syncthreads();

    // ---- Phase 7: density L1 (K=224 -> kt<7, hi/lo) + color L1 (K=256) ----
    f32x4 accs[4][2], accc[4][2];
    {
        int nl = lane & 15;
        #pragma unroll
        for (int q = 0; q < 2; ++q) {
            float bsv = sHb[b * 128 + (2 * w + q) * 16 + nl];
            float bcv = cHb[b * 128 + (2 * w + q) * 16 + nl];
            #pragma unroll
            for (int mt = 0; mt < 4; ++mt) {
                accs[mt][q] = (f32x4){bsv, bsv, bsv, bsv};
                accc[mt][q] = (f32x4){bcv, bcv, bcv, bcv};
            }
        }
        #pragma unroll 1
        for (int kt = 0; kt < 7; ++kt) {
            s16x8 bh0 = *(const s16x8*)&sW1h[(((2 * w    ) * 8 + kt) * 64 + lane) * 8];
            s16x8 bl0 = *(const s16x8*)&sW1l[(((2 * w    ) * 8 + kt) * 64 + lane) * 8];
            s16x8 bh1 = *(const s16x8*)&sW1h[(((2 * w + 1) * 8 + kt) * 64 + lane) * 8];
            s16x8 bl1 = *(const s16x8*)&sW1l[(((2 * w + 1) * 8 + kt) * 64 + lane) * 8];
            #pragma unroll
            for (int mt = 0; mt < 4; ++mt) {
                s16x8 a = *(const s16x8*)&xfrag[swz(XF(kt, mt, lane))];
                accs[mt][0] = MFMA(a, bh0, accs[mt][0]);
                accs[mt][0] = MFMA(a, bl0, accs[mt][0]);
                accs[mt][1] = MFMA(a, bh1, accs[mt][1]);
                accs[mt][1] = MFMA(a, bl1, accs[mt][1]);
            }
        }
        #pragma unroll 1
        for (int kt = 0; kt < 8; ++kt) {
            s16x8 b0 = *(const s16x8*)&cW1f[(((2 * w    ) * 8 + kt) * 64 + lane) * 8];
            s16x8 b1 = *(const s16x8*)&cW1f[(((2 * w + 1) * 8 + kt) * 64 + lane) * 8];
            #pragma unroll
            for (int mt = 0; mt < 4; ++mt) {
                s16x8 a = *(const s16x8*)&xfrag[swz(XF(kt, mt, lane))];
                accc[mt][0] = MFMA(a, b0, accc[mt][0]);
                accc[mt][1] = MFMA(a, b1, accc[mt][1]);
            }
        }
    }
    __syncthreads();

    // ---- Phase 8: relu -> H_s frags (kt 0..3), H_c frags (kt 4..7) ----
    {
        #pragma unroll
        for (int q = 0; q < 2; ++q) {
            int j = (2 * w + q) * 16 + (lane & 15);
            #pragma unroll
            for (int mt = 0; mt < 4; ++mt)
                #pragma unroll
                for (int i = 0; i < 4; ++i) {
                    int p = mt * 16 + ((lane >> 4) << 2) + i;
                    xfrag[fragAddr(p, j)]       = f2bf(fmaxf(accs[mt][q][i], 0.f));
                    xfrag[fragAddr(p, 128 + j)] = f2bf(fmaxf(accc[mt][q][i], 0.f));
                }
        }
    }
    __syncthreads();

    // ---- Phase 9: density L2 + color L2 (K=128 each; wave w -> mt=w) ----
    {
        f32x4 as = (f32x4){0, 0, 0, 0};
        f32x4 ac = (f32x4){0, 0, 0, 0};
        #pragma unroll
        for (int kt = 0; kt < 4; ++kt) {
            s16x8 bsv = *(const s16x8*)&sW2f[(kt * 64 + lane) * 8];
            s16x8 bcv = *(const s16x8*)&cW2f[(kt * 64 + lane) * 8];
            s16x8 a1 = *(const s16x8*)&xfrag[swz(XF(kt, w, lane))];
            s16x8 a2 = *(const s16x8*)&xfrag[swz(XF(4 + kt, w, lane))];
            as = MFMA(a1, bsv, as);
            ac = MFMA(a2, bcv, ac);
        }
        int col = lane & 15;
        #pragma unroll
        for (int i = 0; i < 4; ++i) {
            int p = w * 16 + ((lane >> 4) << 2) + i;
            if (col == 0)
                out[6 * NPTS + b * NPTS + n0 + p] = as[i] + sb2[0];
            if (col < 3) {
                float v = ac[i] + cb2[col];
                out[8 * NPTS + (b * 3 + col) * NPTS + n0 + p] =
                    1.f / (1.f + __expf(-v));
            }
        }
    }
}

// ---------------------------------------------------------------------------
extern "C" void kernel_launch(void* const* d_in, const int* in_sizes, int n_in,
                              void* d_out, int out_size, void* d_ws, size_t ws_size,
                              hipStream_t stream) {
    const float* qp   = (const float*)d_in[0];
    const float* qv   = (const float*)d_in[1];
    const float* exp_ = (const float*)d_in[2];
    const float* bs   = (const float*)d_in[3];
    const float* mean = (const float*)d_in[4];
    const float* fvol = (const float*)d_in[5];
    const float* dW1  = (const float*)d_in[6];
    const float* db1  = (const float*)d_in[7];
    const float* dW2  = (const float*)d_in[8];
    const float* db2  = (const float*)d_in[9];
    const float* sW1  = (const float*)d_in[10];
    const float* sb1  = (const float*)d_in[11];
    const float* sW2  = (const float*)d_in[12];
    const float* sb2  = (const float*)d_in[13];
    const float* cW1  = (const float*)d_in[14];
    const float* cb1  = (const float*)d_in[15];
    const float* cW2  = (const float*)d_in[16];
    const float* cb2  = (const float*)d_in[17];

    float* out = (float*)d_out;
    float* ws  = (float*)d_ws;

    float* dvt = ws;                                   // 262144 f
    float* sHb = ws + 262144;                          // 256 f
    float* cHb = ws + 262400;                          // 256 f
    unsigned short* wb = (unsigned short*)(ws + 262656);
    unsigned short* dW1h  = wb;                        // 8192
    unsigned short* dW1l  = wb + 8192;                 // 8192
    unsigned short* sW1h  = wb + 16384;                // 32768
    unsigned short* sW1l  = wb + 49152;                // 32768
    unsigned short* cW1f_ = wb + 81920;                // 32768
    unsigned short* dW2f  = wb + 114688;               // 1024
    unsigned short* sW2f  = wb + 115712;               // 2048
    unsigned short* cW2f  = wb + 117760;               // 2048 (end 119808 u16)
    float* fvt = ws + 262656 + 59904;                  // = ws + 322560
    bool cl = ws_size >= (size_t)(322560 + 2097152) * 4;

    k_deform_vol_t<<<1024, 256, 0, stream>>>(exp_, bs, mean, dvt);
    k_hb<<<2, 128, 0, stream>>>(exp_, sW1, sb1, cW1, cb1, sHb, cHb);
    k_wprep<<<32, 256, 0, stream>>>(dW1, dW1h, dW1l, 4, 64, 128, 1, 8192);
    k_wprep<<<128, 256, 0, stream>>>(sW1, sW1h, sW1l, 8, 128, 216, 0, 32768);
    k_wprep<<<128, 256, 0, stream>>>(cW1, cW1f_, nullptr, 8, 128, 275, 2, 32768);
    k_wprep<<<4, 256, 0, stream>>>(dW2, dW2f, nullptr, 2, 3, 64, 0, 1024);
    k_wprep<<<8, 256, 0, stream>>>(sW2, sW2f, nullptr, 4, 1, 128, 0, 2048);
    k_wprep<<<8, 256, 0, stream>>>(cW2, cW2f, nullptr, 4, 3, 128, 0, 2048);

    if (cl) {
        k_ftr<<<2097152 / 256, 256, 0, stream>>>(fvol, fvt);
        k_main<true><<<8192, 256, 0, stream>>>(
            qp, qv, dvt, fvt, db1, db2, sb2, cb2, sHb, cHb,
            dW1h, dW1l, sW1h, sW1l, cW1f_, dW2f, sW2f, cW2f, out);
    } else {
        k_main<false><<<8192, 256, 0, stream>>>(
            qp, qv, dvt, fvol, db1, db2, sb2, cb2, sHb, cHb,
            dW1h, dW1l, sW1h, sW1l, cW1f_, dW2f, sW2f, cW2f, out);
    }
}

// Round 8
// 271.285 us; speedup vs baseline: 8.2881x; 1.0223x over previous
//
#include <hip/hip_runtime.h>
#include <math.h>

#define NPTS 262144
#define RSTR 66    // raw[] row stride in floats (64 pts + 2 pad)

typedef __attribute__((ext_vector_type(4))) float f32x4;
typedef __attribute__((ext_vector_type(8))) short s16x8;

// Exact round-to-nearest-even f32->bf16 (matches numpy/JAX). Do NOT use
// v_cvt_pk_bf16_f32: proven non-RTNE by round-3/4/5 bisection.
__device__ __forceinline__ unsigned short f2bf(float f) {
    union { float f; unsigned u; } v; v.f = f;
    unsigned u = v.u;
    return (unsigned short)((u + 0x7fffu + ((u >> 16) & 1u)) >> 16);
}
__device__ __forceinline__ float bf2f(unsigned short h) {
    union { unsigned u; float f; } v; v.u = ((unsigned)h) << 16;
    return v.f;
}

// xfrag element-address swizzle: inject bits 7,8 into bank bits 3,4.
// Only bits >=3 touched -> b128-safe; applied to ALL xfrag accesses.
__device__ __forceinline__ int swz(int e) {
    return e ^ (((e >> 7) & 1) << 3) ^ (((e >> 8) & 1) << 4);
}

// Linear fragment base (bf16-element units): [kt][mt=4][lane=64][j=8]
__device__ __forceinline__ int XF(int kt, int mt, int lane) {
    return ((kt * 4 + mt) * 64 + lane) * 8;
}

// A-fragment scatter address (swizzled) for mfma_f32_16x16x32_bf16.
// Lane l holds row p = mt*16 + (l&15), k = kt*32 + 4*(l>>4) + (j&3) + 16*(j>>2).
// CSE identities (round-7 lesson — step with XOR, NOT add!):
//   fragAddr(p0+i, k) = fragAddr(p0,k) ^ (8*i)   (i<4, p0&15 multiple of 4;
//     +8i would CARRY into bit 5 when swizzled bits 3/4 are set)
//   fragAddr(p, 128+j) = fragAddr(p,j) + 8192    (bit 13, carry-free)
__device__ __forceinline__ int fragAddr(int p, int k) {
    int kt = k >> 5, kk = k & 31;
    int lane = (((kk & 15) >> 2) << 4) | (p & 15);
    int j = ((kk >> 4) << 2) | (kk & 3);
    int mt = (p >> 4) & 3;
    return swz((((kt * 4 + mt) * 64) + lane) * 8 + j);
}

// ---------------------------------------------------------------------------
__global__ void k_deform_vol_t(const float* __restrict__ exp_,
                               const float* __restrict__ bs,
                               const float* __restrict__ mean,
                               float* __restrict__ dvt) {
    int idx = blockIdx.x * blockDim.x + threadIdx.x;   // 262144
    int c = idx & 3;
    int v = (idx >> 2) & 32767;
    int b = idx >> 17;
    float acc = mean[c * 32768 + v];
    #pragma unroll 8
    for (int e = 0; e < 32; ++e)
        acc = fmaf(exp_[b * 32 + e], bs[(e * 4 + c) * 32768 + v], acc);
    dvt[idx] = acc;
}

__global__ void k_ftr(const float* __restrict__ fvol, float* __restrict__ fvt) {
    int i = blockIdx.x * blockDim.x + threadIdx.x;     // 2097152
    int c = i >> 18;
    int v = i & 262143;
    fvt[v * 8 + c] = fvol[i];
}

__global__ void k_hb(const float* __restrict__ exp_,
                     const float* __restrict__ sW1, const float* __restrict__ sb1,
                     const float* __restrict__ cW1, const float* __restrict__ cb1,
                     float* __restrict__ sHb, float* __restrict__ cHb) {
    int b = blockIdx.x;
    int j = threadIdx.x;           // 128
    float a = sb1[j];
    float a2 = cb1[j];
    for (int e = 0; e < 32; ++e) {
        float ev = exp_[b * 32 + e] * (1.0f / 3.0f);
        a  = fmaf(ev, sW1[(216 + e) * 128 + j], a);
        a2 = fmaf(ev, cW1[(243 + e) * 128 + j], a2);
    }
    sHb[b * 128 + j] = a;
    cHb[b * 128 + j] = a2;
}

// ---------------------------------------------------------------------------
// Weight -> B-fragment tables (bf16, optional hi/lo split).
// K-row mapping (MUST mirror the embed phases exactly):
//  mode 0: identity, row = k < Ksrc ? k : -1
//  mode 1 (dW1, K=128): g=k>>5, t=(k>>4)&1, r=k&15
//          r<12 -> 12+24g+12t+r ; else idx=(2g+t)*4+(r-12), idx<12 -> idx
//  mode 2/3 (sW1/cW1, K=256): g=k>>6, tg=(k>>5)&1, r=k&31
//          r<24      -> 24+48g+24tg+r                      (fe sincos)
//          r=24..26  -> mode3 ? 219+6g+3tg+(r-24) : -1     (ve sincos)
//          r>=27     -> idx=(2g+tg)*5+(r-27):
//                         idx<24 -> idx                    (fe raw)
//                         idx=24..26 && mode3 -> 216+(idx-24) (ve raw)
//                         else -1
// ---------------------------------------------------------------------------
__global__ void k_wprep(const float* __restrict__ src,
                        unsigned short* __restrict__ dhi,
                        unsigned short* __restrict__ dlo,
                        int KT, int Nsrc, int Ksrc, int mode, int total) {
    int i = blockIdx.x * 256 + threadIdx.x;
    if (i >= total) return;
    int j = i & 7, lane = (i >> 3) & 63;
    int tile = i >> 9;
    int kt = tile % KT, nt = tile / KT;
    int n = nt * 16 + (lane & 15);
    int k = kt * 32 + ((lane >> 4) << 2) + (j & 3) + ((j >> 2) << 4);
    int row = -1;
    if (mode == 0) {
        row = (k < Ksrc) ? k : -1;
    } else if (mode == 1) {
        int g = k >> 5, tg = (k >> 4) & 1, r = k & 15;
        if (r < 12) row = 12 + 24 * g + 12 * tg + r;
        else { int idx = (2 * g + tg) * 4 + (r - 12); row = (idx < 12) ? idx : -1; }
    } else {
        int g = k >> 6, tg = (k >> 5) & 1, r = k & 31;
        if (r < 24) row = 24 + 48 * g + 24 * tg + r;
        else if (r < 27) row = (mode == 3) ? 219 + 6 * g + 3 * tg + (r - 24) : -1;
        else {
            int idx = (2 * g + tg) * 5 + (r - 27);
            if (idx < 24) row = idx;
            else if (idx < 27 && mode == 3) row = 216 + (idx - 24);
            else row = -1;
        }
    }
    float v = (row >= 0 && n < Nsrc) ? src[row * Nsrc + n] : 0.0f;
    unsigned short h = f2bf(v);
    dhi[i] = h;
    if (dlo) dlo[i] = f2bf(v - bf2f(h));
}

// ---------------------------------------------------------------------------
template<int S, int STEP, int DIM, int NC>
__device__ __forceinline__ void lerp_cl(const float* __restrict__ vol,
                                        float px, float py, float pz,
                                        float* __restrict__ o) {
    float fx = px * (float)S - 0.5f;
    float fy = py * (float)S - 0.5f;
    float fz = pz * (float)S - 0.5f;
    float x0 = floorf(fx), y0 = floorf(fy), z0 = floorf(fz);
    float wx = fx - x0, wy = fy - y0, wz = fz - z0;
    int ix = (int)x0, iy = (int)y0, iz = (int)z0;
    #pragma unroll
    for (int c = 0; c < NC; ++c) o[c] = 0.0f;
    #pragma unroll
    for (int dz = 0; dz < 2; ++dz)
    #pragma unroll
    for (int dy = 0; dy < 2; ++dy)
    #pragma unroll
    for (int dx = 0; dx < 2; ++dx) {
        int xi = ix + dx, yi = iy + dy, zi = iz + dz;
        bool valid = (xi >= 0) & (xi < S) & (yi >= 0) & (yi < S) & (zi >= 0) & (zi < S);
        int xc = min(max(xi, 0), S - 1);
        int yc = min(max(yi, 0), S - 1);
        int zc = min(max(zi, 0), S - 1);
        float w = (dz ? wz : 1.f - wz) * (dy ? wy : 1.f - wy) * (dx ? wx : 1.f - wx);
        w = valid ? w : 0.f;
        const float4* q = (const float4*)(vol +
            (size_t)(((zc * STEP) * DIM + yc * STEP) * DIM + xc * STEP) * NC);
        float4 v0 = q[0];
        o[0] = fmaf(v0.x, w, o[0]); o[1] = fmaf(v0.y, w, o[1]);
        o[2] = fmaf(v0.z, w, o[2]); o[3] = fmaf(v0.w, w, o[3]);
        if (NC == 8) {
            float4 v1 = q[1];
            o[4] = fmaf(v1.x, w, o[4]); o[5] = fmaf(v1.y, w, o[5]);
            o[6] = fmaf(v1.z, w, o[6]); o[7] = fmaf(v1.w, w, o[7]);
        }
    }
}

template<int C, int BD, int S, int STEP>
__device__ __forceinline__ void trilerp_cm(const float* __restrict__ vol,
                                           float px, float py, float pz,
                                           float* __restrict__ out) {
    float fx = px * (float)S - 0.5f;
    float fy = py * (float)S - 0.5f;
    float fz = pz * (float)S - 0.5f;
    float x0 = floorf(fx), y0 = floorf(fy), z0 = floorf(fz);
    float wx = fx - x0, wy = fy - y0, wz = fz - z0;
    int ix = (int)x0, iy = (int)y0, iz = (int)z0;
    #pragma unroll
    for (int c = 0; c < C; ++c) out[c] = 0.0f;
    #pragma unroll
    for (int dz = 0; dz < 2; ++dz)
    #pragma unroll
    for (int dy = 0; dy < 2; ++dy)
    #pragma unroll
    for (int dx = 0; dx < 2; ++dx) {
        int xi = ix + dx, yi = iy + dy, zi = iz + dz;
        bool valid = (xi >= 0) & (xi < S) & (yi >= 0) & (yi < S) & (zi >= 0) & (zi < S);
        int xc = min(max(xi, 0), S - 1);
        int yc = min(max(yi, 0), S - 1);
        int zc = min(max(zi, 0), S - 1);
        float w = (dz ? wz : 1.f - wz) * (dy ? wy : 1.f - wy) * (dx ? wx : 1.f - wx);
        w = valid ? w : 0.f;
        int off = ((zc * STEP) * BD + yc * STEP) * BD + xc * STEP;
        #pragma unroll
        for (int c = 0; c < C; ++c)
            out[c] = fmaf(vol[c * (BD * BD * BD) + off], w, out[c]);
    }
}

#define MFMA(a, b, c) __builtin_amdgcn_mfma_f32_16x16x32_bf16((a), (b), (c), 0, 0, 0)

// ---------------------------------------------------------------------------
// Main fused kernel: 64 points / block, 256 threads = 4 waves, 4 blocks/CU.
// Permuted K-layouts (modes 1/2/3); double-angle sincos ladders in embeds;
// RTNE f2bf everywhere; swizzled xfrag with XOR-stepped scatter CSE.
// ---------------------------------------------------------------------------
template<bool CL>
__global__ __launch_bounds__(256, 4) void k_main(
    const float* __restrict__ qp, const float* __restrict__ qv,
    const float* __restrict__ dvt, const float* __restrict__ fvol,
    const float* __restrict__ db1, const float* __restrict__ db2,
    const float* __restrict__ sb2, const float* __restrict__ cb2,
    const float* __restrict__ sHb, const float* __restrict__ cHb,
    const unsigned short* __restrict__ dW1h, const unsigned short* __restrict__ dW1l,
    const unsigned short* __restrict__ sW1h, const unsigned short* __restrict__ sW1l,
    const unsigned short* __restrict__ cW1f,
    const unsigned short* __restrict__ dW2f, const unsigned short* __restrict__ sW2f,
    const unsigned short* __restrict__ cW2f,
    float* __restrict__ out)
{
    __shared__ __align__(16) unsigned short xfrag[16384];    // 32 KB
    __shared__ __align__(16) float raw[28 * RSTR];           // 7.4 KB
    __shared__ float dp[3 * 64];                             // 0.75 KB

    const int t = threadIdx.x;
    const int lane = t & 63;
    const int w = t >> 6;
    const int gp0 = blockIdx.x * 64;
    const int b = gp0 / NPTS;
    const int n0 = gp0 - b * NPTS;
    const float* qpb = qp + b * 3 * NPTS;
    const float* qvb = qv + b * 3 * NPTS;

    const int cc = (lane >> 4) << 2;       // 0,4,8,12
    const int pp = w * 16 + (lane & 15);   // this thread's embed point col

    // ---- Phase 1: deform interp -> raw rows 0..11; zero row 12 ----
    {
        const float* dv = dvt + b * 131072;
        if (t < 192) {
            int p = t & 63, lvl = t >> 6;
            int n = n0 + p;
            float px = qpb[n], py = qpb[NPTS + n], pz = qpb[2 * NPTS + n];
            float o[4];
            if (lvl == 0)      lerp_cl<32, 1, 32, 4>(dv, px, py, pz, o);
            else if (lvl == 1) lerp_cl<16, 2, 32, 4>(dv, px, py, pz, o);
            else               lerp_cl< 8, 4, 32, 4>(dv, px, py, pz, o);
            #pragma unroll
            for (int c = 0; c < 4; ++c) raw[(lvl * 4 + c) * RSTR + p] = o[c];
        }
        if (t < 64) raw[12 * RSTR + t] = 0.f;
    }
    __syncthreads();

    // ---- Phase 2: embed deform -> X_d frags (K=128, kt 0..3, mode-1) ----
    {
        float s0[4], c0[4];
        #pragma unroll
        for (int m = 0; m < 4; ++m) {
            float x = raw[min(cc + m, 12) * RSTR + pp];
            s0[m] = __sinf(x);
            c0[m] = __cosf(x);
        }
        #pragma unroll
        for (int g = 0; g < 4; ++g) {
            float vs[8];
            #pragma unroll
            for (int m = 0; m < 4; ++m) {
                int r = cc + m;
                bool lad = r < 12;
                int i0 = (2 * g) * 4 + (r - 12);
                int i1 = (2 * g + 1) * 4 + (r - 12);
                float r0 = raw[min(max(i0, 0), 12) * RSTR + pp];
                float r1 = raw[min(max(i1, 0), 12) * RSTR + pp];
                vs[m]     = lad ? s0[m] : r0;   // j 0..3: t=0 (sin half)
                vs[4 + m] = lad ? c0[m] : r1;   // j 4..7: t=1 (cos half)
            }
            union { unsigned short s[8]; s16x8 v; } pk;
            #pragma unroll
            for (int m = 0; m < 8; ++m) pk.s[m] = f2bf(vs[m]);
            *(s16x8*)&xfrag[swz(XF(g, w, lane))] = pk.v;
            if (g < 3) {
                #pragma unroll
                for (int m = 0; m < 4; ++m) {
                    float s2 = 2.f * s0[m] * c0[m];
                    float c2 = c0[m] * c0[m] - s0[m] * s0[m];
                    s0[m] = s2; c0[m] = c2;
                }
            }
        }
    }
    __syncthreads();

    // ---- Phase 3: dMLP layer1 (K=128, N=64; wave w -> nt=w; hi/lo split) ----
    {
        f32x4 acc[4];
        float bias = db1[w * 16 + (lane & 15)];
        #pragma unroll
        for (int mt = 0; mt < 4; ++mt) acc[mt] = (f32x4){bias, bias, bias, bias};
        #pragma unroll 1
        for (int kt = 0; kt < 4; ++kt) {
            s16x8 bh = *(const s16x8*)&dW1h[((w * 4 + kt) * 64 + lane) * 8];
            s16x8 bl = *(const s16x8*)&dW1l[((w * 4 + kt) * 64 + lane) * 8];
            #pragma unroll
            for (int mt = 0; mt < 4; ++mt) {
                s16x8 a = *(const s16x8*)&xfrag[swz(XF(kt, mt, lane))];
                acc[mt] = MFMA(a, bh, acc[mt]);
                acc[mt] = MFMA(a, bl, acc[mt]);
            }
        }
        // relu -> H_d frags at k = 128 + j (kt 4..5); XOR-stepped scatter
        int j = w * 16 + (lane & 15);
        #pragma unroll
        for (int mt = 0; mt < 4; ++mt) {
            int a0 = fragAddr(mt * 16 + cc, 128 + j);
            #pragma unroll
            for (int i = 0; i < 4; ++i)
                xfrag[a0 ^ (8 * i)] = f2bf(fmaxf(acc[mt][i], 0.f));
        }
    }
    __syncthreads();

    // ---- Phase 4: dMLP layer2 (K=64; wave w -> mt=w) ----
    {
        f32x4 acc = (f32x4){0, 0, 0, 0};
        #pragma unroll
        for (int kt = 0; kt < 2; ++kt) {
            s16x8 bb = *(const s16x8*)&dW2f[(kt * 64 + lane) * 8];
            s16x8 a = *(const s16x8*)&xfrag[swz(XF(4 + kt, w, lane))];
            acc = MFMA(a, bb, acc);
        }
        int col = lane & 15;
        if (col < 3) {
            #pragma unroll
            for (int i = 0; i < 4; ++i) {
                int p = w * 16 + ((lane >> 4) << 2) + i;
                float v = acc[i] + db2[col];
                out[(b * 3 + col) * NPTS + n0 + p] = v;
                dp[col * 64 + p] = fmaf(v, 0.1f, qpb[col * NPTS + n0 + p]);
            }
        }
    }
    __syncthreads();

    // ---- Phase 5: feature interp -> raw 0..23; viewdir 24..26; zero 27 ----
    {
        if (t < 192) {
            int p = t & 63, lvl = t >> 6;
            float px = dp[p], py = dp[64 + p], pz = dp[128 + p];
            float o[8];
            if (CL) {
                if (lvl == 0)      lerp_cl<64, 1, 64, 8>(fvol, px, py, pz, o);
                else if (lvl == 1) lerp_cl<32, 2, 64, 8>(fvol, px, py, pz, o);
                else               lerp_cl<16, 4, 64, 8>(fvol, px, py, pz, o);
            } else {
                if (lvl == 0)      trilerp_cm<8, 64, 64, 1>(fvol, px, py, pz, o);
                else if (lvl == 1) trilerp_cm<8, 64, 32, 2>(fvol, px, py, pz, o);
                else               trilerp_cm<8, 64, 16, 4>(fvol, px, py, pz, o);
            }
            #pragma unroll
            for (int c = 0; c < 8; ++c) raw[(lvl * 8 + c) * RSTR + p] = o[c];
        }
        if (t < 64) {
            int n = n0 + t;
            raw[24 * RSTR + t] = qvb[n];
            raw[25 * RSTR + t] = qvb[NPTS + n];
            raw[26 * RSTR + t] = qvb[2 * NPTS + n];
            raw[27 * RSTR + t] = 0.f;
        }
    }
    __syncthreads();

    // ---- Phase 6: embed feature+view -> X frags (K=256, mode-2/3 layout) ----
    {
        float sL[4], cL[4], sH[4], cH[4];
        #pragma unroll
        for (int m = 0; m < 4; ++m) {
            float xl = raw[(cc + m) * RSTR + pp];
            sL[m] = __sinf(xl); cL[m] = __cosf(xl);
            float xh = raw[min(16 + cc + m, 27) * RSTR + pp];
            sH[m] = __sinf(xh); cH[m] = __cosf(xh);
        }
        #pragma unroll
        for (int g = 0; g < 4; ++g) {
            #pragma unroll
            for (int tg = 0; tg < 2; ++tg) {
                float vs[8];
                #pragma unroll
                for (int m = 0; m < 4; ++m) {
                    vs[m] = tg ? cL[m] : sL[m];
                    int rh = 16 + cc + m;
                    int idx = (2 * g + tg) * 5 + (rh - 27);
                    float rsv = raw[min(max(idx, 0), 27) * RSTR + pp];
                    float lad = tg ? cH[m] : sH[m];
                    vs[4 + m] = (rh < 27) ? lad : rsv;
                }
                union { unsigned short s[8]; s16x8 v; } pk;
                #pragma unroll
                for (int m = 0; m < 8; ++m) pk.s[m] = f2bf(vs[m]);
                *(s16x8*)&xfrag[swz(XF(2 * g + tg, w, lane))] = pk.v;
            }
            if (g < 3) {
                #pragma unroll
                for (int m = 0; m < 4; ++m) {
                    float s2 = 2.f * sL[m] * cL[m];
                    float c2 = cL[m] * cL[m] - sL[m] * sL[m];
                    sL[m] = s2; cL[m] = c2;
                    float s3 = 2.f * sH[m] * cH[m];
                    float c3 = cH[m] * cH[m] - sH[m] * sH[m];
                    sH[m] = s3; cH[m] = c3;
                }
            }
        }
    }
    __syncthreads();

    // ---- Phase 7: density L1 (K=256, hi/lo) + color L1 (K=256) ----
    f32x4 accs[4][2], accc[4][2];
    {
        int nl = lane & 15;
        #pragma unroll
        for (int q = 0; q < 2; ++q) {
            float bsv = sHb[b * 128 + (2 * w + q) * 16 + nl];
            float bcv = cHb[b * 128 + (2 * w + q) * 16 + nl];
            #pragma unroll
            for (int mt = 0; mt < 4; ++mt) {
                accs[mt][q] = (f32x4){bsv, bsv, bsv, bsv};
                accc[mt][q] = (f32x4){bcv, bcv, bcv, bcv};
            }
        }
        #pragma unroll 1
        for (int kt = 0; kt < 8; ++kt) {
            s16x8 bh0 = *(const s16x8*)&sW1h[(((2 * w    ) * 8 + kt) * 64 + lane) * 8];
            s16x8 bl0 = *(const s16x8*)&sW1l[(((2 * w    ) * 8 + kt) * 64 + lane) * 8];
            s16x8 bh1 = *(const s16x8*)&sW1h[(((2 * w + 1) * 8 + kt) * 64 + lane) * 8];
            s16x8 bl1 = *(const s16x8*)&sW1l[(((2 * w + 1) * 8 + kt) * 64 + lane) * 8];
            #pragma unroll
            for (int mt = 0; mt < 4; ++mt) {
                s16x8 a = *(const s16x8*)&xfrag[swz(XF(kt, mt, lane))];
                accs[mt][0] = MFMA(a, bh0, accs[mt][0]);
                accs[mt][0] = MFMA(a, bl0, accs[mt][0]);
                accs[mt][1] = MFMA(a, bh1, accs[mt][1]);
                accs[mt][1] = MFMA(a, bl1, accs[mt][1]);
            }
        }
        #pragma unroll 1
        for (int kt = 0; kt < 8; ++kt) {
            s16x8 b0 = *(const s16x8*)&cW1f[(((2 * w    ) * 8 + kt) * 64 + lane) * 8];
            s16x8 b1 = *(const s16x8*)&cW1f[(((2 * w + 1) * 8 + kt) * 64 + lane) * 8];
            #pragma unroll
            for (int mt = 0; mt < 4; ++mt) {
                s16x8 a = *(const s16x8*)&xfrag[swz(XF(kt, mt, lane))];
                accc[mt][0] = MFMA(a, b0, accc[mt][0]);
                accc[mt][1] = MFMA(a, b1, accc[mt][1]);
            }
        }
    }
    __syncthreads();

    // ---- Phase 8: relu -> H_s frags (kt 0..3), H_c frags (kt 4..7) ----
    // XOR-stepped scatter; color target is +8192 elements (kt+4, carry-free).
    {
        #pragma unroll
        for (int q = 0; q < 2; ++q) {
            int j = (2 * w + q) * 16 + (lane & 15);
            #pragma unroll
            for (int mt = 0; mt < 4; ++mt) {
                int a0 = fragAddr(mt * 16 + cc, j);
                #pragma unroll
                for (int i = 0; i < 4; ++i) {
                    int ai = a0 ^ (8 * i);
                    xfrag[ai]        = f2bf(fmaxf(accs[mt][q][i], 0.f));
                    xfrag[ai + 8192] = f2bf(fmaxf(accc[mt][q][i], 0.f));
                }
            }
        }
    }
    __syncthreads();

    // ---- Phase 9: density L2 + color L2 (K=128 each; wave w -> mt=w) ----
    {
        f32x4 as = (f32x4){0, 0, 0, 0};
        f32x4 ac = (f32x4){0, 0, 0, 0};
        #pragma unroll
        for (int kt = 0; kt < 4; ++kt) {
            s16x8 bsv = *(const s16x8*)&sW2f[(kt * 64 + lane) * 8];
            s16x8 bcv = *(const s16x8*)&cW2f[(kt * 64 + lane) * 8];
            s16x8 a1 = *(const s16x8*)&xfrag[swz(XF(kt, w, lane))];
            s16x8 a2 = *(const s16x8*)&xfrag[swz(XF(4 + kt, w, lane))];
            as = MFMA(a1, bsv, as);
            ac = MFMA(a2, bcv, ac);
        }
        int col = lane & 15;
        #pragma unroll
        for (int i = 0; i < 4; ++i) {
            int p = w * 16 + ((lane >> 4) << 2) + i;
            if (col == 0)
                out[6 * NPTS + b * NPTS + n0 + p] = as[i] + sb2[0];
            if (col < 3) {
                float v = ac[i] + cb2[col];
                out[8 * NPTS + (b * 3 + col) * NPTS + n0 + p] =
                    1.f / (1.f + __expf(-v));
            }
        }
    }
}

// ---------------------------------------------------------------------------
extern "C" void kernel_launch(void* const* d_in, const int* in_sizes, int n_in,
                              void* d_out, int out_size, void* d_ws, size_t ws_size,
                              hipStream_t stream) {
    const float* qp   = (const float*)d_in[0];
    const float* qv   = (const float*)d_in[1];
    const float* exp_ = (const float*)d_in[2];
    const float* bs   = (const float*)d_in[3];
    const float* mean = (const float*)d_in[4];
    const float* fvol = (const float*)d_in[5];
    const float* dW1  = (const float*)d_in[6];
    const float* db1  = (const float*)d_in[7];
    const float* dW2  = (const float*)d_in[8];
    const float* db2  = (const float*)d_in[9];
    const float* sW1  = (const float*)d_in[10];
    const float* sb1  = (const float*)d_in[11];
    const float* sW2  = (const float*)d_in[12];
    const float* sb2  = (const float*)d_in[13];
    const float* cW1  = (const float*)d_in[14];
    const float* cb1  = (const float*)d_in[15];
    const float* cW2  = (const float*)d_in[16];
    const float* cb2  = (const float*)d_in[17];

    float* out = (float*)d_out;
    float* ws  = (float*)d_ws;

    float* dvt = ws;                                   // 262144 f
    float* sHb = ws + 262144;                          // 256 f
    float* cHb = ws + 262400;                          // 256 f
    unsigned short* wb = (unsigned short*)(ws + 262656);
    unsigned short* dW1h  = wb;                        // 8192
    unsigned short* dW1l  = wb + 8192;                 // 8192
    unsigned short* sW1h  = wb + 16384;                // 32768
    unsigned short* sW1l  = wb + 49152;                // 32768
    unsigned short* cW1f_ = wb + 81920;                // 32768
    unsigned short* dW2f  = wb + 114688;               // 1024
    unsigned short* sW2f  = wb + 115712;               // 2048
    unsigned short* cW2f  = wb + 117760;               // 2048 (end 119808 u16)
    float* fvt = ws + 262656 + 59904;                  // = ws + 322560
    bool cl = ws_size >= (size_t)(322560 + 2097152) * 4;

    k_deform_vol_t<<<1024, 256, 0, stream>>>(exp_, bs, mean, dvt);
    k_hb<<<2, 128, 0, stream>>>(exp_, sW1, sb1, cW1, cb1, sHb, cHb);
    k_wprep<<<32, 256, 0, stream>>>(dW1, dW1h, dW1l, 4, 64, 128, 1, 8192);
    k_wprep<<<128, 256, 0, stream>>>(sW1, sW1h, sW1l, 8, 128, 256, 2, 32768);
    k_wprep<<<128, 256, 0, stream>>>(cW1, cW1f_, nullptr, 8, 128, 256, 3, 32768);
    k_wprep<<<4, 256, 0, stream>>>(dW2, dW2f, nullptr, 2, 3, 64, 0, 1024);
    k_wprep<<<8, 256, 0, stream>>>(sW2, sW2f, nullptr, 4, 1, 128, 0, 2048);
    k_wprep<<<8, 256, 0, stream>>>(cW2, cW2f, nullptr, 4, 3, 128, 0, 2048);

    if (cl) {
        k_ftr<<<2097152 / 256, 256, 0, stream>>>(fvol, fvt);
        k_main<true><<<8192, 256, 0, stream>>>(
            qp, qv, dvt, fvt, db1, db2, sb2, cb2, sHb, cHb,
            dW1h, dW1l, sW1h, sW1l, cW1f_, dW2f, sW2f, cW2f, out);
    } else {
        k_main<false><<<8192, 256, 0, stream>>>(
            qp, qv, dvt, fvol, db1, db2, sb2, cb2, sHb, cHb,
            dW1h, dW1l, sW1h, sW1l, cW1f_, dW2f, sW2f, cW2f, out);
    }
}

// Round 9
// 268.531 us; speedup vs baseline: 8.3731x; 1.0103x over previous
//
#include <hip/hip_runtime.h>
#include <math.h>

#define NPTS 262144
#define RSTR 66    // raw[] row stride in floats (64 pts + 2 pad)

typedef __attribute__((ext_vector_type(4))) float f32x4;
typedef __attribute__((ext_vector_type(8))) short s16x8;

// Exact round-to-nearest-even f32->bf16 (matches numpy/JAX). Do NOT use
// v_cvt_pk_bf16_f32: proven non-RTNE by round-3/4/5 bisection.
__device__ __forceinline__ unsigned short f2bf(float f) {
    union { float f; unsigned u; } v; v.f = f;
    unsigned u = v.u;
    return (unsigned short)((u + 0x7fffu + ((u >> 16) & 1u)) >> 16);
}
__device__ __forceinline__ float bf2f(unsigned short h) {
    union { unsigned u; float f; } v; v.u = ((unsigned)h) << 16;
    return v.f;
}

// xfrag element-address swizzle: inject bits 7,8 into bank bits 3,4.
// Only bits >=3 touched -> b128-safe; applied to ALL xfrag accesses.
__device__ __forceinline__ int swz(int e) {
    return e ^ (((e >> 7) & 1) << 3) ^ (((e >> 8) & 1) << 4);
}

// Linear fragment base (bf16-element units): [kt=4][mt=4][lane=64][j=8]
// xfrag is now a 4-kt-tile (16 KB) window; K=256 is processed in two
// chunks of 4 kt (split-K), K=128 H uses kt0..3, K=64 H_d uses kt0..1.
__device__ __forceinline__ int XF(int kt, int mt, int lane) {
    return ((kt * 4 + mt) * 64 + lane) * 8;
}

// A-fragment scatter address (swizzled) for mfma_f32_16x16x32_bf16.
// Lane l holds row p = mt*16 + (l&15), k = kt*32 + 4*(l>>4) + (j&3) + 16*(j>>2).
// CSE identities (round-7 lesson — step with XOR, NOT add!):
//   fragAddr(p0+i, k) = fragAddr(p0,k) ^ (8*i)   (i<4, p0&15 multiple of 4)
__device__ __forceinline__ int fragAddr(int p, int k) {
    int kt = k >> 5, kk = k & 31;
    int lane = (((kk & 15) >> 2) << 4) | (p & 15);
    int j = ((kk >> 4) << 2) | (kk & 3);
    int mt = (p >> 4) & 3;
    return swz((((kt * 4 + mt) * 64) + lane) * 8 + j);
}

// ---------------------------------------------------------------------------
__global__ void k_deform_vol_t(const float* __restrict__ exp_,
                               const float* __restrict__ bs,
                               const float* __restrict__ mean,
                               float* __restrict__ dvt) {
    int idx = blockIdx.x * blockDim.x + threadIdx.x;   // 262144
    int c = idx & 3;
    int v = (idx >> 2) & 32767;
    int b = idx >> 17;
    float acc = mean[c * 32768 + v];
    #pragma unroll 8
    for (int e = 0; e < 32; ++e)
        acc = fmaf(exp_[b * 32 + e], bs[(e * 4 + c) * 32768 + v], acc);
    dvt[idx] = acc;
}

__global__ void k_ftr(const float* __restrict__ fvol, float* __restrict__ fvt) {
    int i = blockIdx.x * blockDim.x + threadIdx.x;     // 2097152
    int c = i >> 18;
    int v = i & 262143;
    fvt[v * 8 + c] = fvol[i];
}

__global__ void k_hb(const float* __restrict__ exp_,
                     const float* __restrict__ sW1, const float* __restrict__ sb1,
                     const float* __restrict__ cW1, const float* __restrict__ cb1,
                     float* __restrict__ sHb, float* __restrict__ cHb) {
    int b = blockIdx.x;
    int j = threadIdx.x;           // 128
    float a = sb1[j];
    float a2 = cb1[j];
    for (int e = 0; e < 32; ++e) {
        float ev = exp_[b * 32 + e] * (1.0f / 3.0f);
        a  = fmaf(ev, sW1[(216 + e) * 128 + j], a);
        a2 = fmaf(ev, cW1[(243 + e) * 128 + j], a2);
    }
    sHb[b * 128 + j] = a;
    cHb[b * 128 + j] = a2;
}

// ---------------------------------------------------------------------------
// Weight -> B-fragment tables (bf16, optional hi/lo split).
// K-row mapping (MUST mirror the embed phases exactly):
//  mode 0: identity, row = k < Ksrc ? k : -1
//  mode 1 (dW1, K=128): g=k>>5, t=(k>>4)&1, r=k&15
//          r<12 -> 12+24g+12t+r ; else idx=(2g+t)*4+(r-12), idx<12 -> idx
//  mode 2/3 (sW1/cW1, K=256): g=k>>6, tg=(k>>5)&1, r=k&31
//          r<24      -> 24+48g+24tg+r                      (fe sincos)
//          r=24..26  -> mode3 ? 219+6g+3tg+(r-24) : -1     (ve sincos)
//          r>=27     -> idx=(2g+tg)*5+(r-27):
//                         idx<24 -> idx                    (fe raw)
//                         idx=24..26 && mode3 -> 216+(idx-24) (ve raw)
//                         else -1
// ---------------------------------------------------------------------------
__global__ void k_wprep(const float* __restrict__ src,
                        unsigned short* __restrict__ dhi,
                        unsigned short* __restrict__ dlo,
                        int KT, int Nsrc, int Ksrc, int mode, int total) {
    int i = blockIdx.x * 256 + threadIdx.x;
    if (i >= total) return;
    int j = i & 7, lane = (i >> 3) & 63;
    int tile = i >> 9;
    int kt = tile % KT, nt = tile / KT;
    int n = nt * 16 + (lane & 15);
    int k = kt * 32 + ((lane >> 4) << 2) + (j & 3) + ((j >> 2) << 4);
    int row = -1;
    if (mode == 0) {
        row = (k < Ksrc) ? k : -1;
    } else if (mode == 1) {
        int g = k >> 5, tg = (k >> 4) & 1, r = k & 15;
        if (r < 12) row = 12 + 24 * g + 12 * tg + r;
        else { int idx = (2 * g + tg) * 4 + (r - 12); row = (idx < 12) ? idx : -1; }
    } else {
        int g = k >> 6, tg = (k >> 5) & 1, r = k & 31;
        if (r < 24) row = 24 + 48 * g + 24 * tg + r;
        else if (r < 27) row = (mode == 3) ? 219 + 6 * g + 3 * tg + (r - 24) : -1;
        else {
            int idx = (2 * g + tg) * 5 + (r - 27);
            if (idx < 24) row = idx;
            else if (idx < 27 && mode == 3) row = 216 + (idx - 24);
            else row = -1;
        }
    }
    float v = (row >= 0 && n < Nsrc) ? src[row * Nsrc + n] : 0.0f;
    unsigned short h = f2bf(v);
    dhi[i] = h;
    if (dlo) dlo[i] = f2bf(v - bf2f(h));
}

// ---------------------------------------------------------------------------
template<int S, int STEP, int DIM, int NC>
__device__ __forceinline__ void lerp_cl(const float* __restrict__ vol,
                                        float px, float py, float pz,
                                        float* __restrict__ o) {
    float fx = px * (float)S - 0.5f;
    float fy = py * (float)S - 0.5f;
    float fz = pz * (float)S - 0.5f;
    float x0 = floorf(fx), y0 = floorf(fy), z0 = floorf(fz);
    float wx = fx - x0, wy = fy - y0, wz = fz - z0;
    int ix = (int)x0, iy = (int)y0, iz = (int)z0;
    #pragma unroll
    for (int c = 0; c < NC; ++c) o[c] = 0.0f;
    #pragma unroll
    for (int dz = 0; dz < 2; ++dz)
    #pragma unroll
    for (int dy = 0; dy < 2; ++dy)
    #pragma unroll
    for (int dx = 0; dx < 2; ++dx) {
        int xi = ix + dx, yi = iy + dy, zi = iz + dz;
        bool valid = (xi >= 0) & (xi < S) & (yi >= 0) & (yi < S) & (zi >= 0) & (zi < S);
        int xc = min(max(xi, 0), S - 1);
        int yc = min(max(yi, 0), S - 1);
        int zc = min(max(zi, 0), S - 1);
        float w = (dz ? wz : 1.f - wz) * (dy ? wy : 1.f - wy) * (dx ? wx : 1.f - wx);
        w = valid ? w : 0.f;
        const float4* q = (const float4*)(vol +
            (size_t)(((zc * STEP) * DIM + yc * STEP) * DIM + xc * STEP) * NC);
        float4 v0 = q[0];
        o[0] = fmaf(v0.x, w, o[0]); o[1] = fmaf(v0.y, w, o[1]);
        o[2] = fmaf(v0.z, w, o[2]); o[3] = fmaf(v0.w, w, o[3]);
        if (NC == 8) {
            float4 v1 = q[1];
            o[4] = fmaf(v1.x, w, o[4]); o[5] = fmaf(v1.y, w, o[5]);
            o[6] = fmaf(v1.z, w, o[6]); o[7] = fmaf(v1.w, w, o[7]);
        }
    }
}

template<int C, int BD, int S, int STEP>
__device__ __forceinline__ void trilerp_cm(const float* __restrict__ vol,
                                           float px, float py, float pz,
                                           float* __restrict__ out) {
    float fx = px * (float)S - 0.5f;
    float fy = py * (float)S - 0.5f;
    float fz = pz * (float)S - 0.5f;
    float x0 = floorf(fx), y0 = floorf(fy), z0 = floorf(fz);
    float wx = fx - x0, wy = fy - y0, wz = fz - z0;
    int ix = (int)x0, iy = (int)y0, iz = (int)z0;
    #pragma unroll
    for (int c = 0; c < C; ++c) out[c] = 0.0f;
    #pragma unroll
    for (int dz = 0; dz < 2; ++dz)
    #pragma unroll
    for (int dy = 0; dy < 2; ++dy)
    #pragma unroll
    for (int dx = 0; dx < 2; ++dx) {
        int xi = ix + dx, yi = iy + dy, zi = iz + dz;
        bool valid = (xi >= 0) & (xi < S) & (yi >= 0) & (yi < S) & (zi >= 0) & (zi < S);
        int xc = min(max(xi, 0), S - 1);
        int yc = min(max(yi, 0), S - 1);
        int zc = min(max(zi, 0), S - 1);
        float w = (dz ? wz : 1.f - wz) * (dy ? wy : 1.f - wy) * (dx ? wx : 1.f - wx);
        w = valid ? w : 0.f;
        int off = ((zc * STEP) * BD + yc * STEP) * BD + xc * STEP;
        #pragma unroll
        for (int c = 0; c < C; ++c)
            out[c] = fmaf(vol[c * (BD * BD * BD) + off], w, out[c]);
    }
}

#define MFMA(a, b, c) __builtin_amdgcn_mfma_f32_16x16x32_bf16((a), (b), (c), 0, 0, 0)

// ---------------------------------------------------------------------------
// Main fused kernel: 64 points / block, 256 threads = 4 waves.
// SPLIT-K: xfrag is a 16 KB 4-kt window; feature K=256 runs as two
// embed->MFMA chunks; H_s / H_c written+consumed sequentially.
// LDS total ~24.5 KB -> up to 6 blocks/CU (was 4 at 40 KB).
// ---------------------------------------------------------------------------
template<bool CL>
__global__ __launch_bounds__(256, 4) void k_main(
    const float* __restrict__ qp, const float* __restrict__ qv,
    const float* __restrict__ dvt, const float* __restrict__ fvol,
    const float* __restrict__ db1, const float* __restrict__ db2,
    const float* __restrict__ sb2, const float* __restrict__ cb2,
    const float* __restrict__ sHb, const float* __restrict__ cHb,
    const unsigned short* __restrict__ dW1h, const unsigned short* __restrict__ dW1l,
    const unsigned short* __restrict__ sW1h, const unsigned short* __restrict__ sW1l,
    const unsigned short* __restrict__ cW1f,
    const unsigned short* __restrict__ dW2f, const unsigned short* __restrict__ sW2f,
    const unsigned short* __restrict__ cW2f,
    float* __restrict__ out)
{
    __shared__ __align__(16) unsigned short xfrag[8192];     // 16 KB (4 kt)
    __shared__ __align__(16) float raw[28 * RSTR];           // 7.4 KB
    __shared__ float dp[3 * 64];                             // 0.75 KB

    const int t = threadIdx.x;
    const int lane = t & 63;
    const int w = t >> 6;
    const int gp0 = blockIdx.x * 64;
    const int b = gp0 / NPTS;
    const int n0 = gp0 - b * NPTS;
    const float* qpb = qp + b * 3 * NPTS;
    const float* qvb = qv + b * 3 * NPTS;

    const int cc = (lane >> 4) << 2;       // 0,4,8,12
    const int pp = w * 16 + (lane & 15);   // this thread's embed point col

    // ---- Phase 1: deform interp -> raw rows 0..11; zero row 12 ----
    {
        const float* dv = dvt + b * 131072;
        if (t < 192) {
            int p = t & 63, lvl = t >> 6;
            int n = n0 + p;
            float px = qpb[n], py = qpb[NPTS + n], pz = qpb[2 * NPTS + n];
            float o[4];
            if (lvl == 0)      lerp_cl<32, 1, 32, 4>(dv, px, py, pz, o);
            else if (lvl == 1) lerp_cl<16, 2, 32, 4>(dv, px, py, pz, o);
            else               lerp_cl< 8, 4, 32, 4>(dv, px, py, pz, o);
            #pragma unroll
            for (int c = 0; c < 4; ++c) raw[(lvl * 4 + c) * RSTR + p] = o[c];
        }
        if (t < 64) raw[12 * RSTR + t] = 0.f;
    }
    __syncthreads();

    // ---- Phase 2: embed deform -> X_d frags (kt 0..3, mode-1 layout) ----
    {
        float s0[4], c0[4];
        #pragma unroll
        for (int m = 0; m < 4; ++m) {
            float x = raw[min(cc + m, 12) * RSTR + pp];
            s0[m] = __sinf(x);
            c0[m] = __cosf(x);
        }
        #pragma unroll
        for (int g = 0; g < 4; ++g) {
            float vs[8];
            #pragma unroll
            for (int m = 0; m < 4; ++m) {
                int r = cc + m;
                bool lad = r < 12;
                int i0 = (2 * g) * 4 + (r - 12);
                int i1 = (2 * g + 1) * 4 + (r - 12);
                float r0 = raw[min(max(i0, 0), 12) * RSTR + pp];
                float r1 = raw[min(max(i1, 0), 12) * RSTR + pp];
                vs[m]     = lad ? s0[m] : r0;
                vs[4 + m] = lad ? c0[m] : r1;
            }
            union { unsigned short s[8]; s16x8 v; } pk;
            #pragma unroll
            for (int m = 0; m < 8; ++m) pk.s[m] = f2bf(vs[m]);
            *(s16x8*)&xfrag[swz(XF(g, w, lane))] = pk.v;
            if (g < 3) {
                #pragma unroll
                for (int m = 0; m < 4; ++m) {
                    float s2 = 2.f * s0[m] * c0[m];
                    float c2 = c0[m] * c0[m] - s0[m] * s0[m];
                    s0[m] = s2; c0[m] = c2;
                }
            }
        }
    }
    __syncthreads();

    // ---- Phase 3: dMLP L1 (K=128; wave w -> nt=w; hi/lo split) ----
    {
        f32x4 acc[4];
        float bias = db1[w * 16 + (lane & 15)];
        #pragma unroll
        for (int mt = 0; mt < 4; ++mt) acc[mt] = (f32x4){bias, bias, bias, bias};
        #pragma unroll 1
        for (int kt = 0; kt < 4; ++kt) {
            s16x8 bh = *(const s16x8*)&dW1h[((w * 4 + kt) * 64 + lane) * 8];
            s16x8 bl = *(const s16x8*)&dW1l[((w * 4 + kt) * 64 + lane) * 8];
            #pragma unroll
            for (int mt = 0; mt < 4; ++mt) {
                s16x8 a = *(const s16x8*)&xfrag[swz(XF(kt, mt, lane))];
                acc[mt] = MFMA(a, bh, acc[mt]);
                acc[mt] = MFMA(a, bl, acc[mt]);
            }
        }
        __syncthreads();   // all waves finished reading X_d before overwrite
        // relu -> H_d frags at local kt 0..1 (k = j, 0..63); XOR-step scatter
        int j = w * 16 + (lane & 15);
        #pragma unroll
        for (int mt = 0; mt < 4; ++mt) {
            int a0 = fragAddr(mt * 16 + cc, j);
            #pragma unroll
            for (int i = 0; i < 4; ++i)
                xfrag[a0 ^ (8 * i)] = f2bf(fmaxf(acc[mt][i], 0.f));
        }
    }
    __syncthreads();

    // ---- Phase 4: dMLP L2 (K=64, H_d at kt 0..1; wave w -> mt=w) ----
    {
        f32x4 acc = (f32x4){0, 0, 0, 0};
        #pragma unroll
        for (int kt = 0; kt < 2; ++kt) {
            s16x8 bb = *(const s16x8*)&dW2f[(kt * 64 + lane) * 8];
            s16x8 a = *(const s16x8*)&xfrag[swz(XF(kt, w, lane))];
            acc = MFMA(a, bb, acc);
        }
        int col = lane & 15;
        if (col < 3) {
            #pragma unroll
            for (int i = 0; i < 4; ++i) {
                int p = w * 16 + ((lane >> 4) << 2) + i;
                float v = acc[i] + db2[col];
                out[(b * 3 + col) * NPTS + n0 + p] = v;
                dp[col * 64 + p] = fmaf(v, 0.1f, qpb[col * NPTS + n0 + p]);
            }
        }
    }
    __syncthreads();

    // ---- Phase 5: feature interp -> raw 0..23; viewdir 24..26; zero 27 ----
    {
        if (t < 192) {
            int p = t & 63, lvl = t >> 6;
            float px = dp[p], py = dp[64 + p], pz = dp[128 + p];
            float o[8];
            if (CL) {
                if (lvl == 0)      lerp_cl<64, 1, 64, 8>(fvol, px, py, pz, o);
                else if (lvl == 1) lerp_cl<32, 2, 64, 8>(fvol, px, py, pz, o);
                else               lerp_cl<16, 4, 64, 8>(fvol, px, py, pz, o);
            } else {
                if (lvl == 0)      trilerp_cm<8, 64, 64, 1>(fvol, px, py, pz, o);
                else if (lvl == 1) trilerp_cm<8, 64, 32, 2>(fvol, px, py, pz, o);
                else               trilerp_cm<8, 64, 16, 4>(fvol, px, py, pz, o);
            }
            #pragma unroll
            for (int c = 0; c < 8; ++c) raw[(lvl * 8 + c) * RSTR + p] = o[c];
        }
        if (t < 64) {
            int n = n0 + t;
            raw[24 * RSTR + t] = qvb[n];
            raw[25 * RSTR + t] = qvb[NPTS + n];
            raw[26 * RSTR + t] = qvb[2 * NPTS + n];
            raw[27 * RSTR + t] = 0.f;
        }
    }
    __syncthreads();

    // ---- Phase 6+7: SPLIT-K feature embed + L1 MFMA, two chunks of 4 kt ----
    f32x4 accs[4][2], accc[4][2];
    {
        int nl = lane & 15;
        #pragma unroll
        for (int q = 0; q < 2; ++q) {
            float bsv = sHb[b * 128 + (2 * w + q) * 16 + nl];
            float bcv = cHb[b * 128 + (2 * w + q) * 16 + nl];
            #pragma unroll
            for (int mt = 0; mt < 4; ++mt) {
                accs[mt][q] = (f32x4){bsv, bsv, bsv, bsv};
                accc[mt][q] = (f32x4){bcv, bcv, bcv, bcv};
            }
        }
        float sL[4], cL[4], sH[4], cH[4];
        #pragma unroll
        for (int m = 0; m < 4; ++m) {
            float xl = raw[(cc + m) * RSTR + pp];
            sL[m] = __sinf(xl); cL[m] = __cosf(xl);
            float xh = raw[min(16 + cc + m, 27) * RSTR + pp];
            sH[m] = __sinf(xh); cH[m] = __cosf(xh);
        }
        #pragma unroll
        for (int chunk = 0; chunk < 2; ++chunk) {
            // embed 4 kt (global kt = chunk*4 .. chunk*4+3) into the window
            #pragma unroll
            for (int gg = 0; gg < 2; ++gg) {
                const int g = chunk * 2 + gg;
                #pragma unroll
                for (int tg = 0; tg < 2; ++tg) {
                    float vs[8];
                    #pragma unroll
                    for (int m = 0; m < 4; ++m) {
                        vs[m] = tg ? cL[m] : sL[m];
                        int rh = 16 + cc + m;
                        int idx = (2 * g + tg) * 5 + (rh - 27);
                        float rsv = raw[min(max(idx, 0), 27) * RSTR + pp];
                        float lad = tg ? cH[m] : sH[m];
                        vs[4 + m] = (rh < 27) ? lad : rsv;
                    }
                    union { unsigned short s[8]; s16x8 v; } pk;
                    #pragma unroll
                    for (int m = 0; m < 8; ++m) pk.s[m] = f2bf(vs[m]);
                    *(s16x8*)&xfrag[swz(XF(2 * gg + tg, w, lane))] = pk.v;
                }
                if (g < 3) {
                    #pragma unroll
                    for (int m = 0; m < 4; ++m) {
                        float s2 = 2.f * sL[m] * cL[m];
                        float c2 = cL[m] * cL[m] - sL[m] * sL[m];
                        sL[m] = s2; cL[m] = c2;
                        float s3 = 2.f * sH[m] * cH[m];
                        float c3 = cH[m] * cH[m] - sH[m] * sH[m];
                        sH[m] = s3; cH[m] = c3;
                    }
                }
            }
            __syncthreads();
            // density L1 accumulate over this chunk (hi/lo)
            #pragma unroll 1
            for (int ktl = 0; ktl < 4; ++ktl) {
                const int ktg = chunk * 4 + ktl;
                s16x8 bh0 = *(const s16x8*)&sW1h[(((2 * w    ) * 8 + ktg) * 64 + lane) * 8];
                s16x8 bl0 = *(const s16x8*)&sW1l[(((2 * w    ) * 8 + ktg) * 64 + lane) * 8];
                s16x8 bh1 = *(const s16x8*)&sW1h[(((2 * w + 1) * 8 + ktg) * 64 + lane) * 8];
                s16x8 bl1 = *(const s16x8*)&sW1l[(((2 * w + 1) * 8 + ktg) * 64 + lane) * 8];
                #pragma unroll
                for (int mt = 0; mt < 4; ++mt) {
                    s16x8 a = *(const s16x8*)&xfrag[swz(XF(ktl, mt, lane))];
                    accs[mt][0] = MFMA(a, bh0, accs[mt][0]);
                    accs[mt][0] = MFMA(a, bl0, accs[mt][0]);
                    accs[mt][1] = MFMA(a, bh1, accs[mt][1]);
                    accs[mt][1] = MFMA(a, bl1, accs[mt][1]);
                }
            }
            // color L1 accumulate over this chunk
            #pragma unroll 1
            for (int ktl = 0; ktl < 4; ++ktl) {
                const int ktg = chunk * 4 + ktl;
                s16x8 b0 = *(const s16x8*)&cW1f[(((2 * w    ) * 8 + ktg) * 64 + lane) * 8];
                s16x8 b1 = *(const s16x8*)&cW1f[(((2 * w + 1) * 8 + ktg) * 64 + lane) * 8];
                #pragma unroll
                for (int mt = 0; mt < 4; ++mt) {
                    s16x8 a = *(const s16x8*)&xfrag[swz(XF(ktl, mt, lane))];
                    accc[mt][0] = MFMA(a, b0, accc[mt][0]);
                    accc[mt][1] = MFMA(a, b1, accc[mt][1]);
                }
            }
            __syncthreads();
        }
    }

    // ---- Phase 8a: relu -> H_s frags (kt 0..3) ----
    {
        #pragma unroll
        for (int q = 0; q < 2; ++q) {
            int j = (2 * w + q) * 16 + (lane & 15);
            #pragma unroll
            for (int mt = 0; mt < 4; ++mt) {
                int a0 = fragAddr(mt * 16 + cc, j);
                #pragma unroll
                for (int i = 0; i < 4; ++i)
                    xfrag[a0 ^ (8 * i)] = f2bf(fmaxf(accs[mt][q][i], 0.f));
            }
        }
    }
    __syncthreads();

    // ---- Phase 9a: density L2 (K=128, kt 0..3; wave w -> mt=w) ----
    {
        f32x4 as = (f32x4){0, 0, 0, 0};
        #pragma unroll
        for (int kt = 0; kt < 4; ++kt) {
            s16x8 bsv = *(const s16x8*)&sW2f[(kt * 64 + lane) * 8];
            s16x8 a1 = *(const s16x8*)&xfrag[swz(XF(kt, w, lane))];
            as = MFMA(a1, bsv, as);
        }
        int col = lane & 15;
        if (col == 0) {
            #pragma unroll
            for (int i = 0; i < 4; ++i) {
                int p = w * 16 + ((lane >> 4) << 2) + i;
                out[6 * NPTS + b * NPTS + n0 + p] = as[i] + sb2[0];
            }
        }
    }
    __syncthreads();

    // ---- Phase 8b: relu -> H_c frags (kt 0..3, same window) ----
    {
        #pragma unroll
        for (int q = 0; q < 2; ++q) {
            int j = (2 * w + q) * 16 + (lane & 15);
            #pragma unroll
            for (int mt = 0; mt < 4; ++mt) {
                int a0 = fragAddr(mt * 16 + cc, j);
                #pragma unroll
                for (int i = 0; i < 4; ++i)
                    xfrag[a0 ^ (8 * i)] = f2bf(fmaxf(accc[mt][q][i], 0.f));
            }
        }
    }
    __syncthreads();

    // ---- Phase 9b: color L2 (K=128, kt 0..3; wave w -> mt=w) ----
    {
        f32x4 ac = (f32x4){0, 0, 0, 0};
        #pragma unroll
        for (int kt = 0; kt < 4; ++kt) {
            s16x8 bcv = *(const s16x8*)&cW2f[(kt * 64 + lane) * 8];
            s16x8 a2 = *(const s16x8*)&xfrag[swz(XF(kt, w, lane))];
            ac = MFMA(a2, bcv, ac);
        }
        int col = lane & 15;
        if (col < 3) {
            #pragma unroll
            for (int i = 0; i < 4; ++i) {
                int p = w * 16 + ((lane >> 4) << 2) + i;
                float v = ac[i] + cb2[col];
                out[8 * NPTS + (b * 3 + col) * NPTS + n0 + p] =
                    1.f / (1.f + __expf(-v));
            }
        }
    }
}

// ---------------------------------------------------------------------------
extern "C" void kernel_launch(void* const* d_in, const int* in_sizes, int n_in,
                              void* d_out, int out_size, void* d_ws, size_t ws_size,
                              hipStream_t stream) {
    const float* qp   = (const float*)d_in[0];
    const float* qv   = (const float*)d_in[1];
    const float* exp_ = (const float*)d_in[2];
    const float* bs   = (const float*)d_in[3];
    const float* mean = (const float*)d_in[4];
    const float* fvol = (const float*)d_in[5];
    const float* dW1  = (const float*)d_in[6];
    const float* db1  = (const float*)d_in[7];
    const float* dW2  = (const float*)d_in[8];
    const float* db2  = (const float*)d_in[9];
    const float* sW1  = (const float*)d_in[10];
    const float* sb1  = (const float*)d_in[11];
    const float* sW2  = (const float*)d_in[12];
    const float* sb2  = (const float*)d_in[13];
    const float* cW1  = (const float*)d_in[14];
    const float* cb1  = (const float*)d_in[15];
    const float* cW2  = (const float*)d_in[16];
    const float* cb2  = (const float*)d_in[17];

    float* out = (float*)d_out;
    float* ws  = (float*)d_ws;

    float* dvt = ws;                                   // 262144 f
    float* sHb = ws + 262144;                          // 256 f
    float* cHb = ws + 262400;                          // 256 f
    unsigned short* wb = (unsigned short*)(ws + 262656);
    unsigned short* dW1h  = wb;                        // 8192
    unsigned short* dW1l  = wb + 8192;                 // 8192
    unsigned short* sW1h  = wb + 16384;                // 32768
    unsigned short* sW1l  = wb + 49152;                // 32768
    unsigned short* cW1f_ = wb + 81920;                // 32768
    unsigned short* dW2f  = wb + 114688;               // 1024
    unsigned short* sW2f  = wb + 115712;               // 2048
    unsigned short* cW2f  = wb + 117760;               // 2048 (end 119808 u16)
    float* fvt = ws + 262656 + 59904;                  // = ws + 322560
    bool cl = ws_size >= (size_t)(322560 + 2097152) * 4;

    k_deform_vol_t<<<1024, 256, 0, stream>>>(exp_, bs, mean, dvt);
    k_hb<<<2, 128, 0, stream>>>(exp_, sW1, sb1, cW1, cb1, sHb, cHb);
    k_wprep<<<32, 256, 0, stream>>>(dW1, dW1h, dW1l, 4, 64, 128, 1, 8192);
    k_wprep<<<128, 256, 0, stream>>>(sW1, sW1h, sW1l, 8, 128, 256, 2, 32768);
    k_wprep<<<128, 256, 0, stream>>>(cW1, cW1f_, nullptr, 8, 128, 256, 3, 32768);
    k_wprep<<<4, 256, 0, stream>>>(dW2, dW2f, nullptr, 2, 3, 64, 0, 1024);
    k_wprep<<<8, 256, 0, stream>>>(sW2, sW2f, nullptr, 4, 1, 128, 0, 2048);
    k_wprep<<<8, 256, 0, stream>>>(cW2, cW2f, nullptr, 4, 3, 128, 0, 2048);

    if (cl) {
        k_ftr<<<2097152 / 256, 256, 0, stream>>>(fvol, fvt);
        k_main<true><<<8192, 256, 0, stream>>>(
            qp, qv, dvt, fvt, db1, db2, sb2, cb2, sHb, cHb,
            dW1h, dW1l, sW1h, sW1l, cW1f_, dW2f, sW2f, cW2f, out);
    } else {
        k_main<false><<<8192, 256, 0, stream>>>(
            qp, qv, dvt, fvol, db1, db2, sb2, cb2, sHb, cHb,
            dW1h, dW1l, sW1h, sW1l, cW1f_, dW2f, sW2f, cW2f, out);
    }
}

// Round 10
// 253.395 us; speedup vs baseline: 8.8733x; 1.0597x over previous
//
#include <hip/hip_runtime.h>
#include <math.h>

#define NPTS 262144
#define RSTR 66    // raw[] row stride in floats (64 pts + 2 pad)

typedef __attribute__((ext_vector_type(4))) float f32x4;
typedef __attribute__((ext_vector_type(8))) short s16x8;

// Exact round-to-nearest-even f32->bf16 (matches numpy/JAX). Do NOT use
// v_cvt_pk_bf16_f32: proven non-RTNE by round-3/4/5 bisection.
__device__ __forceinline__ unsigned short f2bf(float f) {
    union { float f; unsigned u; } v; v.f = f;
    unsigned u = v.u;
    return (unsigned short)((u + 0x7fffu + ((u >> 16) & 1u)) >> 16);
}
__device__ __forceinline__ float bf2f(unsigned short h) {
    union { unsigned u; float f; } v; v.u = ((unsigned)h) << 16;
    return v.f;
}
// RTNE-rounded bits; hi16 of this IS f2bf. Pair-pack two via v_perm_b32
// (bit-exact with f2bf, fewer VALU ops than shift/and/or).
__device__ __forceinline__ unsigned rnd16(float f) {
    union { float f; unsigned u; } v; v.f = f;
    return v.u + 0x7fffu + ((v.u >> 16) & 1u);
}
__device__ __forceinline__ unsigned packbf(float lo, float hi) {
#if defined(__has_builtin)
#if __has_builtin(__builtin_amdgcn_perm)
    // dst = {hi.b3, hi.b2, lo.b3, lo.b2}; sel codes 0-3 = src1, 4-7 = src0
    return __builtin_amdgcn_perm(rnd16(hi), rnd16(lo), 0x07060302u);
#else
    return (rnd16(hi) & 0xffff0000u) | (rnd16(lo) >> 16);
#endif
#else
    return (rnd16(hi) & 0xffff0000u) | (rnd16(lo) >> 16);
#endif
}

// xfrag element-address swizzle: inject bits 7,8 into bank bits 3,4.
// Only bits >=3 touched -> b128-safe; applied to ALL xfrag accesses.
__device__ __forceinline__ int swz(int e) {
    return e ^ (((e >> 7) & 1) << 3) ^ (((e >> 8) & 1) << 4);
}

// Linear fragment base (bf16-element units): [kt=8][mt=4][lane=64][j=8]
__device__ __forceinline__ int XF(int kt, int mt, int lane) {
    return ((kt * 4 + mt) * 64 + lane) * 8;
}

// A-fragment scatter address (swizzled) for mfma_f32_16x16x32_bf16.
// Lane l holds row p = mt*16 + (l&15), k = kt*32 + 4*(l>>4) + (j&3) + 16*(j>>2).
// CSE identities (round-7 lesson — step with XOR, NOT add!):
//   fragAddr(p0+i, k) = fragAddr(p0,k) ^ (8*i)   (i<4, p0&15 multiple of 4)
//   fragAddr(p, 128+j) = fragAddr(p,j) + 8192    (bit 13, carry-free)
__device__ __forceinline__ int fragAddr(int p, int k) {
    int kt = k >> 5, kk = k & 31;
    int lane = (((kk & 15) >> 2) << 4) | (p & 15);
    int j = ((kk >> 4) << 2) | (kk & 3);
    int mt = (p >> 4) & 3;
    return swz((((kt * 4 + mt) * 64) + lane) * 8 + j);
}

// ---------------------------------------------------------------------------
__global__ void k_deform_vol_t(const float* __restrict__ exp_,
                               const float* __restrict__ bs,
                               const float* __restrict__ mean,
                               float* __restrict__ dvt) {
    int idx = blockIdx.x * blockDim.x + threadIdx.x;   // 262144
    int c = idx & 3;
    int v = (idx >> 2) & 32767;
    int b = idx >> 17;
    float acc = mean[c * 32768 + v];
    #pragma unroll 8
    for (int e = 0; e < 32; ++e)
        acc = fmaf(exp_[b * 32 + e], bs[(e * 4 + c) * 32768 + v], acc);
    dvt[idx] = acc;
}

__global__ void k_ftr(const float* __restrict__ fvol, float* __restrict__ fvt) {
    int i = blockIdx.x * blockDim.x + threadIdx.x;     // 2097152
    int c = i >> 18;
    int v = i & 262143;
    fvt[v * 8 + c] = fvol[i];
}

__global__ void k_hb(const float* __restrict__ exp_,
                     const float* __restrict__ sW1, const float* __restrict__ sb1,
                     const float* __restrict__ cW1, const float* __restrict__ cb1,
                     float* __restrict__ sHb, float* __restrict__ cHb) {
    int b = blockIdx.x;
    int j = threadIdx.x;           // 128
    float a = sb1[j];
    float a2 = cb1[j];
    for (int e = 0; e < 32; ++e) {
        float ev = exp_[b * 32 + e] * (1.0f / 3.0f);
        a  = fmaf(ev, sW1[(216 + e) * 128 + j], a);
        a2 = fmaf(ev, cW1[(243 + e) * 128 + j], a2);
    }
    sHb[b * 128 + j] = a;
    cHb[b * 128 + j] = a2;
}

// ---------------------------------------------------------------------------
// Weight -> B-fragment tables (bf16, optional hi/lo split).
// K-row mapping (MUST mirror the embed phases exactly):
//  mode 0: identity, row = k < Ksrc ? k : -1
//  mode 1 (dW1, K=128): g=k>>5, t=(k>>4)&1, r=k&15
//          r<12 -> 12+24g+12t+r ; else idx=(2g+t)*4+(r-12), idx<12 -> idx
//  mode 2/3 (sW1/cW1, K=256): g=k>>6, tg=(k>>5)&1, r=k&31
//          r<24      -> 24+48g+24tg+r                      (fe sincos)
//          r=24..26  -> mode3 ? 219+6g+3tg+(r-24) : -1     (ve sincos)
//          r>=27     -> idx=(2g+tg)*5+(r-27):
//                         idx<24 -> idx                    (fe raw)
//                         idx=24..26 && mode3 -> 216+(idx-24) (ve raw)
//                         else -1
// ---------------------------------------------------------------------------
__global__ void k_wprep(const float* __restrict__ src,
                        unsigned short* __restrict__ dhi,
                        unsigned short* __restrict__ dlo,
                        int KT, int Nsrc, int Ksrc, int mode, int total) {
    int i = blockIdx.x * 256 + threadIdx.x;
    if (i >= total) return;
    int j = i & 7, lane = (i >> 3) & 63;
    int tile = i >> 9;
    int kt = tile % KT, nt = tile / KT;
    int n = nt * 16 + (lane & 15);
    int k = kt * 32 + ((lane >> 4) << 2) + (j & 3) + ((j >> 2) << 4);
    int row = -1;
    if (mode == 0) {
        row = (k < Ksrc) ? k : -1;
    } else if (mode == 1) {
        int g = k >> 5, tg = (k >> 4) & 1, r = k & 15;
        if (r < 12) row = 12 + 24 * g + 12 * tg + r;
        else { int idx = (2 * g + tg) * 4 + (r - 12); row = (idx < 12) ? idx : -1; }
    } else {
        int g = k >> 6, tg = (k >> 5) & 1, r = k & 31;
        if (r < 24) row = 24 + 48 * g + 24 * tg + r;
        else if (r < 27) row = (mode == 3) ? 219 + 6 * g + 3 * tg + (r - 24) : -1;
        else {
            int idx = (2 * g + tg) * 5 + (r - 27);
            if (idx < 24) row = idx;
            else if (idx < 27 && mode == 3) row = 216 + (idx - 24);
            else row = -1;
        }
    }
    float v = (row >= 0 && n < Nsrc) ? src[row * Nsrc + n] : 0.0f;
    unsigned short h = f2bf(v);
    dhi[i] = h;
    if (dlo) dlo[i] = f2bf(v - bf2f(h));
}

// ---------------------------------------------------------------------------
template<int S, int STEP, int DIM, int NC>
__device__ __forceinline__ void lerp_cl(const float* __restrict__ vol,
                                        float px, float py, float pz,
                                        float* __restrict__ o) {
    float fx = px * (float)S - 0.5f;
    float fy = py * (float)S - 0.5f;
    float fz = pz * (float)S - 0.5f;
    float x0 = floorf(fx), y0 = floorf(fy), z0 = floorf(fz);
    float wx = fx - x0, wy = fy - y0, wz = fz - z0;
    int ix = (int)x0, iy = (int)y0, iz = (int)z0;
    #pragma unroll
    for (int c = 0; c < NC; ++c) o[c] = 0.0f;
    #pragma unroll
    for (int dz = 0; dz < 2; ++dz)
    #pragma unroll
    for (int dy = 0; dy < 2; ++dy)
    #pragma unroll
    for (int dx = 0; dx < 2; ++dx) {
        int xi = ix + dx, yi = iy + dy, zi = iz + dz;
        bool valid = (xi >= 0) & (xi < S) & (yi >= 0) & (yi < S) & (zi >= 0) & (zi < S);
        int xc = min(max(xi, 0), S - 1);
        int yc = min(max(yi, 0), S - 1);
        int zc = min(max(zi, 0), S - 1);
        float w = (dz ? wz : 1.f - wz) * (dy ? wy : 1.f - wy) * (dx ? wx : 1.f - wx);
        w = valid ? w : 0.f;
        const float4* q = (const float4*)(vol +
            (size_t)(((zc * STEP) * DIM + yc * STEP) * DIM + xc * STEP) * NC);
        float4 v0 = q[0];
        o[0] = fmaf(v0.x, w, o[0]); o[1] = fmaf(v0.y, w, o[1]);
        o[2] = fmaf(v0.z, w, o[2]); o[3] = fmaf(v0.w, w, o[3]);
        if (NC == 8) {
            float4 v1 = q[1];
            o[4] = fmaf(v1.x, w, o[4]); o[5] = fmaf(v1.y, w, o[5]);
            o[6] = fmaf(v1.z, w, o[6]); o[7] = fmaf(v1.w, w, o[7]);
        }
    }
}

template<int C, int BD, int S, int STEP>
__device__ __forceinline__ void trilerp_cm(const float* __restrict__ vol,
                                           float px, float py, float pz,
                                           float* __restrict__ out) {
    float fx = px * (float)S - 0.5f;
    float fy = py * (float)S - 0.5f;
    float fz = pz * (float)S - 0.5f;
    float x0 = floorf(fx), y0 = floorf(fy), z0 = floorf(fz);
    float wx = fx - x0, wy = fy - y0, wz = fz - z0;
    int ix = (int)x0, iy = (int)y0, iz = (int)z0;
    #pragma unroll
    for (int c = 0; c < C; ++c) out[c] = 0.0f;
    #pragma unroll
    for (int dz = 0; dz < 2; ++dz)
    #pragma unroll
    for (int dy = 0; dy < 2; ++dy)
    #pragma unroll
    for (int dx = 0; dx < 2; ++dx) {
        int xi = ix + dx, yi = iy + dy, zi = iz + dz;
        bool valid = (xi >= 0) & (xi < S) & (yi >= 0) & (yi < S) & (zi >= 0) & (zi < S);
        int xc = min(max(xi, 0), S - 1);
        int yc = min(max(yi, 0), S - 1);
        int zc = min(max(zi, 0), S - 1);
        float w = (dz ? wz : 1.f - wz) * (dy ? wy : 1.f - wy) * (dx ? wx : 1.f - wx);
        w = valid ? w : 0.f;
        int off = ((zc * STEP) * BD + yc * STEP) * BD + xc * STEP;
        #pragma unroll
        for (int c = 0; c < C; ++c)
            out[c] = fmaf(vol[c * (BD * BD * BD) + off], w, out[c]);
    }
}

#define MFMA(a, b, c) __builtin_amdgcn_mfma_f32_16x16x32_bf16((a), (b), (c), 0, 0, 0)

// ---------------------------------------------------------------------------
// Main fused kernel: 64 points / block, 256 threads = 4 waves.
// Round-8 single 8-kt window (register file caps occupancy at 4 waves/SIMD,
// so 40 KB LDS is free: 4 blocks x 40 KB = 160 KB). sW1 single-bf16 (no
// hi/lo; dW1 keeps the split — offset feeds back with 10-70x amplification).
// Permuted K-layouts (modes 1/2/3); double-angle sincos ladders;
// RTNE f2bf / packbf; swizzled xfrag with XOR-stepped scatter.
// ---------------------------------------------------------------------------
template<bool CL>
__global__ __launch_bounds__(256, 4) void k_main(
    const float* __restrict__ qp, const float* __restrict__ qv,
    const float* __restrict__ dvt, const float* __restrict__ fvol,
    const float* __restrict__ db1, const float* __restrict__ db2,
    const float* __restrict__ sb2, const float* __restrict__ cb2,
    const float* __restrict__ sHb, const float* __restrict__ cHb,
    const unsigned short* __restrict__ dW1h, const unsigned short* __restrict__ dW1l,
    const unsigned short* __restrict__ sW1h,
    const unsigned short* __restrict__ cW1f,
    const unsigned short* __restrict__ dW2f, const unsigned short* __restrict__ sW2f,
    const unsigned short* __restrict__ cW2f,
    float* __restrict__ out)
{
    __shared__ __align__(16) unsigned short xfrag[16384];    // 32 KB (8 kt)
    __shared__ __align__(16) float raw[28 * RSTR];           // 7.4 KB
    __shared__ float dp[3 * 64];                             // 0.75 KB

    const int t = threadIdx.x;
    const int lane = t & 63;
    const int w = t >> 6;
    const int gp0 = blockIdx.x * 64;
    const int b = gp0 / NPTS;
    const int n0 = gp0 - b * NPTS;
    const float* qpb = qp + b * 3 * NPTS;
    const float* qvb = qv + b * 3 * NPTS;

    const int cc = (lane >> 4) << 2;       // 0,4,8,12
    const int pp = w * 16 + (lane & 15);   // this thread's embed point col

    // ---- Phase 1: deform interp -> raw rows 0..11; zero row 12 ----
    {
        const float* dv = dvt + b * 131072;
        if (t < 192) {
            int p = t & 63, lvl = t >> 6;
            int n = n0 + p;
            float px = qpb[n], py = qpb[NPTS + n], pz = qpb[2 * NPTS + n];
            float o[4];
            if (lvl == 0)      lerp_cl<32, 1, 32, 4>(dv, px, py, pz, o);
            else if (lvl == 1) lerp_cl<16, 2, 32, 4>(dv, px, py, pz, o);
            else               lerp_cl< 8, 4, 32, 4>(dv, px, py, pz, o);
            #pragma unroll
            for (int c = 0; c < 4; ++c) raw[(lvl * 4 + c) * RSTR + p] = o[c];
        }
        if (t < 64) raw[12 * RSTR + t] = 0.f;
    }
    __syncthreads();

    // ---- Phase 2: embed deform -> X_d frags (kt 0..3, mode-1 layout) ----
    {
        float s0[4], c0[4];
        #pragma unroll
        for (int m = 0; m < 4; ++m) {
            float x = raw[min(cc + m, 12) * RSTR + pp];
            s0[m] = __sinf(x);
            c0[m] = __cosf(x);
        }
        #pragma unroll
        for (int g = 0; g < 4; ++g) {
            float vs[8];
            #pragma unroll
            for (int m = 0; m < 4; ++m) {
                int r = cc + m;
                bool lad = r < 12;
                int i0 = (2 * g) * 4 + (r - 12);
                int i1 = (2 * g + 1) * 4 + (r - 12);
                float r0 = raw[min(max(i0, 0), 12) * RSTR + pp];
                float r1 = raw[min(max(i1, 0), 12) * RSTR + pp];
                vs[m]     = lad ? s0[m] : r0;
                vs[4 + m] = lad ? c0[m] : r1;
            }
            union { unsigned u[4]; s16x8 v; } pk;
            pk.u[0] = packbf(vs[0], vs[1]);
            pk.u[1] = packbf(vs[2], vs[3]);
            pk.u[2] = packbf(vs[4], vs[5]);
            pk.u[3] = packbf(vs[6], vs[7]);
            *(s16x8*)&xfrag[swz(XF(g, w, lane))] = pk.v;
            if (g < 3) {
                #pragma unroll
                for (int m = 0; m < 4; ++m) {
                    float s2 = 2.f * s0[m] * c0[m];
                    float c2 = c0[m] * c0[m] - s0[m] * s0[m];
                    s0[m] = s2; c0[m] = c2;
                }
            }
        }
    }
    __syncthreads();

    // ---- Phase 3: dMLP L1 (K=128; wave w -> nt=w; hi/lo split kept) ----
    {
        f32x4 acc[4];
        float bias = db1[w * 16 + (lane & 15)];
        #pragma unroll
        for (int mt = 0; mt < 4; ++mt) acc[mt] = (f32x4){bias, bias, bias, bias};
        #pragma unroll 1
        for (int kt = 0; kt < 4; ++kt) {
            s16x8 bh = *(const s16x8*)&dW1h[((w * 4 + kt) * 64 + lane) * 8];
            s16x8 bl = *(const s16x8*)&dW1l[((w * 4 + kt) * 64 + lane) * 8];
            #pragma unroll
            for (int mt = 0; mt < 4; ++mt) {
                s16x8 a = *(const s16x8*)&xfrag[swz(XF(kt, mt, lane))];
                acc[mt] = MFMA(a, bh, acc[mt]);
                acc[mt] = MFMA(a, bl, acc[mt]);
            }
        }
        // relu -> H_d frags at k = 128 + j (kt 4..5); XOR-step scatter
        int j = w * 16 + (lane & 15);
        #pragma unroll
        for (int mt = 0; mt < 4; ++mt) {
            int a0 = fragAddr(mt * 16 + cc, 128 + j);
            #pragma unroll
            for (int i = 0; i < 4; ++i)
                xfrag[a0 ^ (8 * i)] = f2bf(fmaxf(acc[mt][i], 0.f));
        }
    }
    __syncthreads();

    // ---- Phase 4: dMLP L2 (K=64, H_d at kt 4..5; wave w -> mt=w) ----
    {
        f32x4 acc = (f32x4){0, 0, 0, 0};
        #pragma unroll
        for (int kt = 0; kt < 2; ++kt) {
            s16x8 bb = *(const s16x8*)&dW2f[(kt * 64 + lane) * 8];
            s16x8 a = *(const s16x8*)&xfrag[swz(XF(4 + kt, w, lane))];
            acc = MFMA(a, bb, acc);
        }
        int col = lane & 15;
        if (col < 3) {
            #pragma unroll
            for (int i = 0; i < 4; ++i) {
                int p = w * 16 + ((lane >> 4) << 2) + i;
                float v = acc[i] + db2[col];
                out[(b * 3 + col) * NPTS + n0 + p] = v;
                dp[col * 64 + p] = fmaf(v, 0.1f, qpb[col * NPTS + n0 + p]);
            }
        }
    }
    __syncthreads();

    // ---- Phase 5: feature interp -> raw 0..23; viewdir 24..26; zero 27 ----
    {
        if (t < 192) {
            int p = t & 63, lvl = t >> 6;
            float px = dp[p], py = dp[64 + p], pz = dp[128 + p];
            float o[8];
            if (CL) {
                if (lvl == 0)      lerp_cl<64, 1, 64, 8>(fvol, px, py, pz, o);
                else if (lvl == 1) lerp_cl<32, 2, 64, 8>(fvol, px, py, pz, o);
                else               lerp_cl<16, 4, 64, 8>(fvol, px, py, pz, o);
            } else {
                if (lvl == 0)      trilerp_cm<8, 64, 64, 1>(fvol, px, py, pz, o);
                else if (lvl == 1) trilerp_cm<8, 64, 32, 2>(fvol, px, py, pz, o);
                else               trilerp_cm<8, 64, 16, 4>(fvol, px, py, pz, o);
            }
            #pragma unroll
            for (int c = 0; c < 8; ++c) raw[(lvl * 8 + c) * RSTR + p] = o[c];
        }
        if (t < 64) {
            int n = n0 + t;
            raw[24 * RSTR + t] = qvb[n];
            raw[25 * RSTR + t] = qvb[NPTS + n];
            raw[26 * RSTR + t] = qvb[2 * NPTS + n];
            raw[27 * RSTR + t] = 0.f;
        }
    }
    __syncthreads();

    // ---- Phase 6: embed feature+view -> X frags (K=256, mode-2/3 layout) ----
    {
        float sL[4], cL[4], sH[4], cH[4];
        #pragma unroll
        for (int m = 0; m < 4; ++m) {
            float xl = raw[(cc + m) * RSTR + pp];
            sL[m] = __sinf(xl); cL[m] = __cosf(xl);
            float xh = raw[min(16 + cc + m, 27) * RSTR + pp];
            sH[m] = __sinf(xh); cH[m] = __cosf(xh);
        }
        #pragma unroll
        for (int g = 0; g < 4; ++g) {
            #pragma unroll
            for (int tg = 0; tg < 2; ++tg) {
                float vs[8];
                #pragma unroll
                for (int m = 0; m < 4; ++m) {
                    vs[m] = tg ? cL[m] : sL[m];
                    int rh = 16 + cc + m;
                    int idx = (2 * g + tg) * 5 + (rh - 27);
                    float rsv = raw[min(max(idx, 0), 27) * RSTR + pp];
                    float lad = tg ? cH[m] : sH[m];
                    vs[4 + m] = (rh < 27) ? lad : rsv;
                }
                union { unsigned u[4]; s16x8 v; } pk;
                pk.u[0] = packbf(vs[0], vs[1]);
                pk.u[1] = packbf(vs[2], vs[3]);
                pk.u[2] = packbf(vs[4], vs[5]);
                pk.u[3] = packbf(vs[6], vs[7]);
                *(s16x8*)&xfrag[swz(XF(2 * g + tg, w, lane))] = pk.v;
            }
            if (g < 3) {
                #pragma unroll
                for (int m = 0; m < 4; ++m) {
                    float s2 = 2.f * sL[m] * cL[m];
                    float c2 = cL[m] * cL[m] - sL[m] * sL[m];
                    sL[m] = s2; cL[m] = c2;
                    float s3 = 2.f * sH[m] * cH[m];
                    float c3 = cH[m] * cH[m] - sH[m] * sH[m];
                    sH[m] = s3; cH[m] = c3;
                }
            }
        }
    }
    __syncthreads();

    // ---- Phase 7: density L1 (K=256, single bf16) + color L1 (K=256) ----
    f32x4 accs[4][2], accc[4][2];
    {
        int nl = lane & 15;
        #pragma unroll
        for (int q = 0; q < 2; ++q) {
            float bsv = sHb[b * 128 + (2 * w + q) * 16 + nl];
            float bcv = cHb[b * 128 + (2 * w + q) * 16 + nl];
            #pragma unroll
            for (int mt = 0; mt < 4; ++mt) {
                accs[mt][q] = (f32x4){bsv, bsv, bsv, bsv};
                accc[mt][q] = (f32x4){bcv, bcv, bcv, bcv};
            }
        }
        #pragma unroll 1
        for (int kt = 0; kt < 8; ++kt) {
            s16x8 bh0 = *(const s16x8*)&sW1h[(((2 * w    ) * 8 + kt) * 64 + lane) * 8];
            s16x8 bh1 = *(const s16x8*)&sW1h[(((2 * w + 1) * 8 + kt) * 64 + lane) * 8];
            #pragma unroll
            for (int mt = 0; mt < 4; ++mt) {
                s16x8 a = *(const s16x8*)&xfrag[swz(XF(kt, mt, lane))];
                accs[mt][0] = MFMA(a, bh0, accs[mt][0]);
                accs[mt][1] = MFMA(a, bh1, accs[mt][1]);
            }
        }
        #pragma unroll 1
        for (int kt = 0; kt < 8; ++kt) {
            s16x8 b0 = *(const s16x8*)&cW1f[(((2 * w    ) * 8 + kt) * 64 + lane) * 8];
            s16x8 b1 = *(const s16x8*)&cW1f[(((2 * w + 1) * 8 + kt) * 64 + lane) * 8];
            #pragma unroll
            for (int mt = 0; mt < 4; ++mt) {
                s16x8 a = *(const s16x8*)&xfrag[swz(XF(kt, mt, lane))];
                accc[mt][0] = MFMA(a, b0, accc[mt][0]);
                accc[mt][1] = MFMA(a, b1, accc[mt][1]);
            }
        }
    }
    __syncthreads();

    // ---- Phase 8: relu -> H_s frags (kt 0..3), H_c frags (kt 4..7) ----
    // XOR-stepped scatter; color target is +8192 elements (kt+4, carry-free).
    {
        #pragma unroll
        for (int q = 0; q < 2; ++q) {
            int j = (2 * w + q) * 16 + (lane & 15);
            #pragma unroll
            for (int mt = 0; mt < 4; ++mt) {
                int a0 = fragAddr(mt * 16 + cc, j);
                #pragma unroll
                for (int i = 0; i < 4; ++i) {
                    int ai = a0 ^ (8 * i);
                    xfrag[ai]        = f2bf(fmaxf(accs[mt][q][i], 0.f));
                    xfrag[ai + 8192] = f2bf(fmaxf(accc[mt][q][i], 0.f));
                }
            }
        }
    }
    __syncthreads();

    // ---- Phase 9: density L2 + color L2 (K=128 each; wave w -> mt=w) ----
    {
        f32x4 as = (f32x4){0, 0, 0, 0};
        f32x4 ac = (f32x4){0, 0, 0, 0};
        #pragma unroll
        for (int kt = 0; kt < 4; ++kt) {
            s16x8 bsv = *(const s16x8*)&sW2f[(kt * 64 + lane) * 8];
            s16x8 bcv = *(const s16x8*)&cW2f[(kt * 64 + lane) * 8];
            s16x8 a1 = *(const s16x8*)&xfrag[swz(XF(kt, w, lane))];
            s16x8 a2 = *(const s16x8*)&xfrag[swz(XF(4 + kt, w, lane))];
            as = MFMA(a1, bsv, as);
            ac = MFMA(a2, bcv, ac);
        }
        int col = lane & 15;
        #pragma unroll
        for (int i = 0; i < 4; ++i) {
            int p = w * 16 + ((lane >> 4) << 2) + i;
            if (col == 0)
                out[6 * NPTS + b * NPTS + n0 + p] = as[i] + sb2[0];
            if (col < 3) {
                float v = ac[i] + cb2[col];
                out[8 * NPTS + (b * 3 + col) * NPTS + n0 + p] =
                    1.f / (1.f + __expf(-v));
            }
        }
    }
}

// ---------------------------------------------------------------------------
extern "C" void kernel_launch(void* const* d_in, const int* in_sizes, int n_in,
                              void* d_out, int out_size, void* d_ws, size_t ws_size,
                              hipStream_t stream) {
    const float* qp   = (const float*)d_in[0];
    const float* qv   = (const float*)d_in[1];
    const float* exp_ = (const float*)d_in[2];
    const float* bs   = (const float*)d_in[3];
    const float* mean = (const float*)d_in[4];
    const float* fvol = (const float*)d_in[5];
    const float* dW1  = (const float*)d_in[6];
    const float* db1  = (const float*)d_in[7];
    const float* dW2  = (const float*)d_in[8];
    const float* db2  = (const float*)d_in[9];
    const float* sW1  = (const float*)d_in[10];
    const float* sb1  = (const float*)d_in[11];
    const float* sW2  = (const float*)d_in[12];
    const float* sb2  = (const float*)d_in[13];
    const float* cW1  = (const float*)d_in[14];
    const float* cb1  = (const float*)d_in[15];
    const float* cW2  = (const float*)d_in[16];
    const float* cb2  = (const float*)d_in[17];

    float* out = (float*)d_out;
    float* ws  = (float*)d_ws;

    float* dvt = ws;                                   // 262144 f
    float* sHb = ws + 262144;                          // 256 f
    float* cHb = ws + 262400;                          // 256 f
    unsigned short* wb = (unsigned short*)(ws + 262656);
    unsigned short* dW1h  = wb;                        // 8192
    unsigned short* dW1l  = wb + 8192;                 // 8192
    unsigned short* sW1h  = wb + 16384;                // 32768
    unsigned short* cW1f_ = wb + 49152;                // 32768
    unsigned short* dW2f  = wb + 81920;                // 1024
    unsigned short* sW2f  = wb + 82944;                // 2048
    unsigned short* cW2f  = wb + 84992;                // 2048 (end 87040 u16)
    float* fvt = ws + 262656 + 43520;                  // = ws + 306176
    bool cl = ws_size >= (size_t)(306176 + 2097152) * 4;

    k_deform_vol_t<<<1024, 256, 0, stream>>>(exp_, bs, mean, dvt);
    k_hb<<<2, 128, 0, stream>>>(exp_, sW1, sb1, cW1, cb1, sHb, cHb);
    k_wprep<<<32, 256, 0, stream>>>(dW1, dW1h, dW1l, 4, 64, 128, 1, 8192);
    k_wprep<<<128, 256, 0, stream>>>(sW1, sW1h, nullptr, 8, 128, 256, 2, 32768);
    k_wprep<<<128, 256, 0, stream>>>(cW1, cW1f_, nullptr, 8, 128, 256, 3, 32768);
    k_wprep<<<4, 256, 0, stream>>>(dW2, dW2f, nullptr, 2, 3, 64, 0, 1024);
    k_wprep<<<8, 256, 0, stream>>>(sW2, sW2f, nullptr, 4, 1, 128, 0, 2048);
    k_wprep<<<8, 256, 0, stream>>>(cW2, cW2f, nullptr, 4, 3, 128, 0, 2048);

    if (cl) {
        k_ftr<<<2097152 / 256, 256, 0, stream>>>(fvol, fvt);
        k_main<true><<<8192, 256, 0, stream>>>(
            qp, qv, dvt, fvt, db1, db2, sb2, cb2, sHb, cHb,
            dW1h, dW1l, sW1h, cW1f_, dW2f, sW2f, cW2f, out);
    } else {
        k_main<false><<<8192, 256, 0, stream>>>(
            qp, qv, dvt, fvol, db1, db2, sb2, cb2, sHb, cHb,
            dW1h, dW1l, sW1h, cW1f_, dW2f, sW2f, cW2f, out);
    }
}